// Round 9
// baseline (307.853 us; speedup 1.0000x reference)
//
#include <hip/hip_runtime.h>

// ---------------------------------------------------------------------------
// MultiScaleFeatureFusion — R24 (= R23 + attn double-buffered DMA staging).
//   scale0: x1 [4,512,16,16]  d=64 C=512 hs=16 Ns=256  R=161
//   scale1: x2 [4,256,32,32]  d=32 C=256 hs=32 Ns=1024 R=97
//   scale2: x3 [4,128,64,64]  d=16 C=128 hs=64 Ns=4096 R=65
// attn: k/s staged via __builtin_amdgcn_global_load_lds (direct global->LDS
// DMA, no staging VGPRs) into a double buffer: DMA for stage s+1 issues
// right after the stage-s barrier and lands during stage-s compute -> ONE
// barrier per stage, per-stage L2 latency hidden. R16/R23's two-barrier
// single-buffer exposed the full load latency every stage (latency-bound:
// occ 45%, MFMA 33%, VALU 44%, no pipe saturated). VGPR stays ~44 (R17's
// register-prefetch variant paid +16 VGPR -> spill cliff). Compute order
// bit-identical to R16/R23.
// ---------------------------------------------------------------------------

#define BB 4
#define LOG2E 1.44269504088896340736f

typedef __attribute__((ext_vector_type(8))) short short8;
typedef __attribute__((ext_vector_type(4))) float f32x4;

static constexpr int OFF_UP0 = 0;                        // [4][512]
static constexpr int OFF_UP1 = OFF_UP0 + 4 * 512;
static constexpr int OFF_UP2 = OFF_UP1 + 4 * 256;
static constexpr int OFF_UB0 = OFF_UP2 + 4 * 128;
static constexpr int OFF_UB1 = OFF_UB0 + 4;
static constexpr int OFF_UB2 = OFF_UB1 + 4;
static constexpr int OFF_PROJ0 = OFF_UB2 + 4;
static constexpr int OFF_PROJ1 = OFF_PROJ0 + BB * 161 * 256;
static constexpr int OFF_PROJ2 = OFF_PROJ1 + BB * 97 * 1024;
static constexpr int OFF_SBIG0 = OFF_PROJ2 + BB * 65 * 4096;   // [b][4096]
static constexpr int OFF_SBIG1 = OFF_SBIG0 + BB * 4096;        // [b][4096]
static constexpr int OFF_QP0 = OFF_SBIG1 + BB * 4096;          // BB*4096*64 fl
static constexpr int OFF_KF0 = OFF_QP0 + BB * 4096 * 64;       // BB*262144 fl
static constexpr int OFF_QP1 = OFF_KF0 + BB * 262144;          // BB*4096*32 fl
static constexpr int OFF_KF1 = OFF_QP1 + BB * 4096 * 32;       // BB*131072 fl
static constexpr int OFF_QP2 = OFF_KF1 + BB * 131072;          // BB*4096*16 fl
static constexpr int OFF_KF2 = OFF_QP2 + BB * 4096 * 16;       // BB*131072 fl
static constexpr int PS = BB * 4 * 4096;
static constexpr int OFF_PSN0 = OFF_KF2 + BB * 131072;
static constexpr int OFF_PSW0 = OFF_PSN0 + PS;
static constexpr int OFF_PSN1 = OFF_PSW0 + PS;
static constexpr int OFF_PSW1 = OFF_PSN1 + PS;
static constexpr int OFF_PSN2 = OFF_PSW1 + PS;
static constexpr int OFF_PSW2 = OFF_PSN2 + PS;

// ---- direct global->LDS DMA helpers (size literal; dest = base+lane*sz) ---
__device__ inline void gload_lds16(const void* g, void* l) {
    __builtin_amdgcn_global_load_lds((const __attribute__((address_space(1))) void*)g,
                                     (__attribute__((address_space(3))) void*)l, 16, 0, 0);
}
__device__ inline void gload_lds4(const void* g, void* l) {
    __builtin_amdgcn_global_load_lds((const __attribute__((address_space(1))) void*)g,
                                     (__attribute__((address_space(3))) void*)l, 4, 0, 0);
}

// --------------------------- u partials ------------------------------------
struct UArgs {
    const float *wv0, *wa0, *bv0;
    const float *wv1, *wa1, *bv1;
    const float *wv2, *wa2, *bv2;
    float* ws;
};

__global__ void u_kernel(UArgs A) {
    __shared__ float red[256];
    int idx = blockIdx.x, tid = threadIdx.x;
    int C, cit, chunk;
    const float *wv, *wa, *bv;
    float *up, *ub;
    if (idx < 32) {
        C = 512; cit = idx >> 2; chunk = idx & 3;
        wv = A.wv0; wa = A.wa0; bv = A.bv0;
        up = A.ws + OFF_UP0; ub = A.ws + OFF_UB0;
    } else if (idx < 48) {
        int i2 = idx - 32;
        C = 256; cit = i2 >> 2; chunk = i2 & 3;
        wv = A.wv1; wa = A.wa1; bv = A.bv1;
        up = A.ws + OFF_UP1; ub = A.ws + OFF_UB1;
    } else {
        int i2 = idx - 48;
        C = 128; cit = i2 >> 2; chunk = i2 & 3;
        wv = A.wv2; wa = A.wa2; bv = A.bv2;
        up = A.ws + OFF_UP2; ub = A.ws + OFF_UB2;
    }
    int lci = tid & 63, sub = tid >> 6;
    int ci = cit * 64 + lci;
    int coBeg = chunk * (C >> 2), coEnd = coBeg + (C >> 2);
    float acc = 0.f;
#pragma unroll 4
    for (int co = coBeg + sub; co < coEnd; co += 4)
        acc += wa[co] * wv[(size_t)co * C + ci];
    red[tid] = acc;
    __syncthreads();
    if (sub == 0)
        up[chunk * C + ci] = red[lci] + red[lci + 64] + red[lci + 128] + red[lci + 192];
    if (cit == 0) {
        __syncthreads();
        float bacc = 0.f;
        for (int co = coBeg + tid; co < coEnd; co += 256) bacc += wa[co] * bv[co];
        red[tid] = bacc;
        __syncthreads();
        for (int off = 128; off > 0; off >>= 1) {
            if (tid < off) red[tid] += red[tid + off];
            __syncthreads();
        }
        if (tid == 0) ub[chunk] = red[0];
    }
}

// --------------------------- proj: all scales, 16 rows/block, 2 m/thread ---
struct ProjArgs {
    const float *x0, *x1, *x2;
    const float *wq0, *wk0, *bq0, *bk0;
    const float *wq1, *wk1, *bq1, *bk1;
    const float *wq2, *wk2, *bq2, *bk2;
    const float *w1;
    float* ws;
};

__global__ __launch_bounds__(256) void proj_kernel(ProjArgs A) {
    __shared__ __align__(16) float Wl[512 * 16];  // [c][rr]
    __shared__ float bl[16];
    __shared__ float red[2048];
    int idx = blockIdx.x, tid = threadIdx.x;
    const float *x, *wq, *wk, *bq, *bk, *up, *ub;
    float* out;
    int C, Ns, R, nx, d, w1off, local;
    if (idx < 88) {
        local = idx; x = A.x0; out = A.ws + OFF_PROJ0;
        wq = A.wq0; wk = A.wk0; bq = A.bq0; bk = A.bk0;
        up = A.ws + OFF_UP0; ub = A.ws + OFF_UB0;
        C = 512; Ns = 256; R = 161; nx = 2; d = 64; w1off = 384;
    } else if (idx < 312) {
        local = idx - 88; x = A.x1; out = A.ws + OFF_PROJ1;
        wq = A.wq1; wk = A.wk1; bq = A.bq1; bk = A.bk1;
        up = A.ws + OFF_UP1; ub = A.ws + OFF_UB1;
        C = 256; Ns = 1024; R = 97; nx = 8; d = 32; w1off = 128;
    } else {
        local = idx - 312; x = A.x2; out = A.ws + OFF_PROJ2;
        wq = A.wq2; wk = A.wk2; bq = A.bq2; bk = A.bk2;
        up = A.ws + OFF_UP2; ub = A.ws + OFF_UB2;
        C = 128; Ns = 4096; R = 65; nx = 32; d = 16; w1off = 0;
    }
    int ny = (R + 15) >> 4;
    int pb = nx * ny;
    int b = local / pb;
    int rem = local - b * pb;
    int by = rem / nx;
    int bx = rem - by * nx;
    int r0 = by * 16;
    int nr = min(16, R - r0);
    for (int rp = 0; rp < 16; rp += 8) {
        int rr = rp + (tid >> 5), cg = tid & 31;
        int gr = r0 + rr;
        if (gr == 2 * d) {
            for (int c = cg; c < C; c += 32)
                Wl[c * 16 + rr] = up[c] + up[C + c] + up[2 * C + c] + up[3 * C + c];
        } else {
            const float* rowsrc;
            if (gr < d) rowsrc = wq + (size_t)gr * C;
            else if (gr < 2 * d) rowsrc = wk + (size_t)(gr - d) * C;
            else if (gr < R) rowsrc = A.w1 + (size_t)(gr - 2 * d - 1) * 896 + w1off;
            else rowsrc = nullptr;
            if (rowsrc) {
                for (int c = cg; c < C; c += 32) Wl[c * 16 + rr] = rowsrc[c];
            } else {
                for (int c = cg; c < C; c += 32) Wl[c * 16 + rr] = 0.f;
            }
        }
    }
    if (tid < 16) {
        int g2 = r0 + tid;
        float bv2;
        if (g2 < d) bv2 = bq[g2];
        else if (g2 < 2 * d) bv2 = bk[g2 - d];
        else if (g2 == 2 * d) bv2 = ub[0] + ub[1] + ub[2] + ub[3];
        else bv2 = 0.f;
        bl[tid] = bv2;
    }
    __syncthreads();
    int lane = tid & 63, strip = tid >> 6;
    int m0 = bx * 128 + lane * 2;
    const float* xb = x + (size_t)(b * C) * Ns + m0;
    float acc[16][2];
#pragma unroll
    for (int r = 0; r < 16; ++r) {
        acc[r][0] = 0.f;
        acc[r][1] = 0.f;
    }
    float2 buf[4];
#pragma unroll
    for (int j = 0; j < 4; ++j)
        buf[j] = *(const float2*)&xb[(size_t)(strip + 4 * j) * Ns];
    for (int c0 = strip; c0 < C; c0 += 16) {
#pragma unroll
        for (int j = 0; j < 4; ++j) {
            int c = c0 + 4 * j;
            float2 xv = buf[j];
            int cn = c + 16;
            if (cn < C) buf[j] = *(const float2*)&xb[(size_t)cn * Ns];
            const float* wl = &Wl[c * 16];
#pragma unroll
            for (int r4 = 0; r4 < 4; ++r4) {
                float4 w = *(const float4*)&wl[r4 * 4];
                acc[r4 * 4 + 0][0] += w.x * xv.x; acc[r4 * 4 + 0][1] += w.x * xv.y;
                acc[r4 * 4 + 1][0] += w.y * xv.x; acc[r4 * 4 + 1][1] += w.y * xv.y;
                acc[r4 * 4 + 2][0] += w.z * xv.x; acc[r4 * 4 + 2][1] += w.z * xv.y;
                acc[r4 * 4 + 3][0] += w.w * xv.x; acc[r4 * 4 + 3][1] += w.w * xv.y;
            }
        }
    }
    for (int rp = 0; rp < 16; rp += 4) {
        __syncthreads();
#pragma unroll
        for (int r = 0; r < 4; ++r)
#pragma unroll
            for (int j = 0; j < 2; ++j)
                red[((r * 2 + j) * 4 + strip) * 64 + lane] = acc[rp + r][j];
        __syncthreads();
        int g = tid >> 6;
        int rr2 = rp + g;
        if (rr2 < nr) {
            float v[2];
#pragma unroll
            for (int j = 0; j < 2; ++j) {
                int base = (g * 2 + j) * 256 + lane;
                v[j] = red[base] + red[base + 64] + red[base + 128] + red[base + 192] + bl[rr2];
            }
            float2 v2; v2.x = v[0]; v2.y = v[1];
            *(float2*)&out[(size_t)(b * R + r0 + rr2) * Ns + m0] = v2;
        }
    }
}

// --------------------------- hi/lo split helper ----------------------------
__device__ inline void split_bf16(float f, ushort& hi, ushort& lo) {
    unsigned u = __float_as_uint(f);
    unsigned h = u >> 16;
    float r = f - __uint_as_float(h << 16);
    hi = (ushort)h;
    lo = (ushort)(__float_as_uint(r) >> 16);
}

// --------------------------- bilerp field values ---------------------------
template <int D, int HS>
__device__ void bilerp_vals(const float* __restrict__ proj, int R, int rowbase,
                            float scale, int b, int n, float* vals) {
    constexpr int NS = HS * HS;
    constexpr float f = (float)(HS - 1) / 63.0f;
    int oy = n >> 6, ox = n & 63;
    float cy = oy * f, cx = ox * f;
    int iy0 = min((int)cy, HS - 2);
    int ix0 = min((int)cx, HS - 2);
    float wy = cy - iy0, wx = cx - ix0;
    float w00 = (1.f - wy) * (1.f - wx) * scale, w01 = (1.f - wy) * wx * scale;
    float w10 = wy * (1.f - wx) * scale, w11 = wy * wx * scale;
    const float* pb = proj + ((size_t)b * R + rowbase) * NS + iy0 * HS + ix0;
#pragma unroll
    for (int d = 0; d < D; ++d) {
        const float* p = pb + (size_t)d * NS;
        vals[d] = w00 * p[0] + w01 * p[1] + w10 * p[HS] + w11 * p[HS + 1];
    }
}

// --------------------------- q pack ([n][2D] layout) -----------------------
template <int D>
__device__ void q_store(ushort* __restrict__ dst, const float* vals, int b, int n) {
    ushort outv[2 * D];
#pragma unroll
    for (int d = 0; d < D; ++d) split_bf16(vals[d], outv[d], outv[D + d]);
    ushort* dp = dst + (size_t)(b * 4096 + n) * (2 * D);
#pragma unroll
    for (int i = 0; i < D / 4; ++i)
        ((uint4*)dp)[i] = ((const uint4*)outv)[i];
}

// q pack for scale0, one 32-field chunk (chunk 0: d 0..31, chunk 1: 32..63).
__device__ void q_store_c32(ushort* __restrict__ dst, const float* vals,
                            int b, int n, int chunk) {
    ushort outv[64];
#pragma unroll
    for (int d = 0; d < 32; ++d) split_bf16(vals[d], outv[d], outv[32 + d]);
    ushort* dp = dst + (size_t)(b * 4096 + n) * 128;
#pragma unroll
    for (int i = 0; i < 4; ++i)
        ((uint4*)dp)[chunk * 4 + i] = ((const uint4*)outv)[i];
#pragma unroll
    for (int i = 0; i < 4; ++i)
        ((uint4*)dp)[8 + chunk * 4 + i] = ((const uint4*)outv)[4 + i];
}

// --------------------------- k pack (fragment order) -----------------------
template <int D>
__device__ void k_store(ushort* __restrict__ dst, const float* vals, int b, int n) {
    constexpr int NC = (D == 16) ? 2 : (D / 32) * 2;
    ushort hi[D], lo[D];
#pragma unroll
    for (int d = 0; d < D; ++d) split_bf16(vals[d], hi[d], lo[d]);
    int tile = n >> 4, cc = n & 15;
    ushort* kb = dst + (size_t)b * (256 * NC * 512) + (size_t)tile * (NC * 512);
    if constexpr (D == 16) {
#pragma unroll
        for (int combo = 0; combo < 2; ++combo)
#pragma unroll
            for (int quad = 0; quad < 4; ++quad) {
                const ushort* src = (combo == 0 ? hi : lo) + (quad & 1) * 8;
                ushort* dp = kb + ((size_t)combo * 512 + (quad * 16 + cc) * 8);
                *(uint4*)dp = *(const uint4*)src;
            }
    } else {
#pragma unroll
        for (int h = 0; h < D / 32; ++h)
#pragma unroll
            for (int part = 0; part < 2; ++part) {
                int combo = h * 2 + part;
#pragma unroll
                for (int quad = 0; quad < 4; ++quad) {
                    const ushort* src = (part == 0 ? hi : lo) + h * 32 + quad * 8;
                    ushort* dp = kb + ((size_t)combo * 512 + (quad * 16 + cc) * 8);
                    *(uint4*)dp = *(const uint4*)src;
                }
            }
    }
}

// k pack for scale0, one 32-field chunk (h = chunk): writes combos
// {chunk*2, chunk*2+1} — disjoint across chunks, bit-identical union.
__device__ void k_store_c32(ushort* __restrict__ dst, const float* vals,
                            int b, int n, int chunk) {
    ushort hi[32], lo[32];
#pragma unroll
    for (int d = 0; d < 32; ++d) split_bf16(vals[d], hi[d], lo[d]);
    int tile = n >> 4, cc = n & 15;
    ushort* kb = dst + (size_t)b * (256 * 4 * 512) + (size_t)tile * (4 * 512);
#pragma unroll
    for (int part = 0; part < 2; ++part) {
        int combo = chunk * 2 + part;
#pragma unroll
        for (int quad = 0; quad < 4; ++quad) {
            const ushort* src = (part == 0 ? hi : lo) + quad * 8;
            ushort* dp = kb + ((size_t)combo * 512 + (quad * 16 + cc) * 8);
            *(uint4*)dp = *(const uint4*)src;
        }
    }
}

// --------------------------- native field values (scale2) ------------------
__device__ void nat_vals(const float* __restrict__ proj, int rowbase, float scale,
                         int b, int n, float* vals) {
    const float* pb = proj + ((size_t)b * 65 + rowbase) * 4096 + n;
#pragma unroll
    for (int d = 0; d < 16; ++d) vals[d] = pb[(size_t)d * 4096] * scale;
}

// --------------------------- mid: upsample-s + packs -----------------------
__global__ __launch_bounds__(256) void mid_kernel(float* ws) {
    int idx = blockIdx.x, tid = threadIdx.x;
    if (idx < 128) {
        int gi = idx * 256 + tid;
        int seg = gi >> 14;
        int li = gi & 16383;
        int b = li >> 12, n = li & 4095;
        const float* src;
        float* dst;
        int hs;
        if (seg == 0) { src = ws + OFF_PROJ0 + (b * 161 + 128) * 256;  dst = ws + OFF_SBIG0; hs = 16; }
        else          { src = ws + OFF_PROJ1 + (b * 97 + 64) * 1024;   dst = ws + OFF_SBIG1; hs = 32; }
        int oy = n >> 6, ox = n & 63;
        float f = (float)(hs - 1) / 63.0f;
        float cy = oy * f, cx = ox * f;
        int iy0 = min((int)cy, hs - 2);
        int ix0 = min((int)cx, hs - 2);
        float wy = cy - iy0, wx = cx - ix0;
        float v00 = src[iy0 * hs + ix0], v01 = src[iy0 * hs + ix0 + 1];
        float v10 = src[(iy0 + 1) * hs + ix0], v11 = src[(iy0 + 1) * hs + ix0 + 1];
        float t0 = v00 + wx * (v01 - v00), t1 = v10 + wx * (v11 - v10);
        dst[b * 4096 + n] = t0 + wy * (t1 - t0);
    } else if (idx < 384) {
        int li = idx - 128;               // 0..255: scale0, 2 chunks
        int field = li >> 7;
        int rest = li & 127;
        int b = rest >> 5;
        int nt = (rest >> 1) & 15;
        int chunk = rest & 1;
        int n = nt * 256 + tid;
        float vals[32];
        if (field == 0) {
            bilerp_vals<32, 16>(ws + OFF_PROJ0, 161, chunk * 32, LOG2E, b, n, vals);
            q_store_c32((ushort*)(ws + OFF_QP0), vals, b, n, chunk);
        } else {
            bilerp_vals<32, 16>(ws + OFF_PROJ0, 161, 64 + chunk * 32, 1.0f, b, n, vals);
            k_store_c32((ushort*)(ws + OFF_KF0), vals, b, n, chunk);
        }
    } else if (idx < 512) {
        int li = idx - 384;
        int field = li >> 6, b = (li >> 4) & 3, nt = li & 15;
        int n = nt * 256 + tid;
        float vals[32];
        if (field == 0) {
            bilerp_vals<32, 32>(ws + OFF_PROJ1, 97, 0, LOG2E, b, n, vals);
            q_store<32>((ushort*)(ws + OFF_QP1), vals, b, n);
        } else {
            bilerp_vals<32, 32>(ws + OFF_PROJ1, 97, 32, 1.0f, b, n, vals);
            k_store<32>((ushort*)(ws + OFF_KF1), vals, b, n);
        }
    } else {
        int li = idx - 512;
        int field = li >> 6, b = (li >> 4) & 3, nt = li & 15;
        int n = nt * 256 + tid;
        float vals[16];
        if (field == 0) {
            nat_vals(ws + OFF_PROJ2, 0, LOG2E, b, n, vals);
            q_store<16>((ushort*)(ws + OFF_QP2), vals, b, n);
        } else {
            nat_vals(ws + OFF_PROJ2, 16, 1.0f, b, n, vals);
            k_store<16>((ushort*)(ws + OFF_KF2), vals, b, n);
        }
    }
}

// --------------------------- MFMA attention body ---------------------------
// Double-buffered DMA staging: global_load_lds issues stage s+1's k/s loads
// right after the stage-s barrier; they land in LDS buf[cur^1] during
// stage-s compute. ONE barrier per stage (its vmcnt drain waits on a DMA
// that had the whole compute phase to finish). Zero staging VGPRs.
// Per-element MFMA/exp/accumulation order identical to R16 (bit-exact).
template <int D>
__device__ void attn_mfma_body(const ushort* __restrict__ qp, const ushort* __restrict__ kf,
                               const float* __restrict__ srow,
                               float* __restrict__ pSn, float* __restrict__ pSw,
                               int nblk, int mc, int b, int tid,
                               ushort (*kst)[8192], float (*sst)[128]) {
    constexpr int NC = (D == 16) ? 2 : (D / 32) * 2;
    constexpr int ST = 16 / NC;       // tiles per stage (stage = 16 KB)
    constexpr int NF = (D >= 32) ? (D / 32) : 1;
    constexpr int NSTG = 64 / ST;     // stages per 1024-m chunk
    int wave = tid >> 6, lane = tid & 63;
    int cc = lane & 15, quad = lane >> 4;
    int n0 = (nblk * 4 + wave) * 16;
    const ushort* qn = qp + (size_t)(b * 4096 + n0 + cc) * (2 * D);
    short8 Ah[NF], Al[NF];
    if constexpr (D == 16) {
        Ah[0] = *(const short8*)(qn + quad * 8);   // [qh16|ql16] spans k=0..31
    } else {
#pragma unroll
        for (int h = 0; h < NF; ++h) {
            Ah[h] = *(const short8*)(qn + h * 32 + quad * 8);
            Al[h] = *(const short8*)(qn + D + h * 32 + quad * 8);
        }
    }
    float Sn[4] = {0.f, 0.f, 0.f, 0.f};
    float Sw[4] = {0.f, 0.f, 0.f, 0.f};
    int tbase = mc * 64;
    const uint4* gk = (const uint4*)(kf + (size_t)b * (256 * NC * 512) +
                                     (size_t)tbase * (NC * 512));
    const float* gs = srow + tbase * 16;

    // prologue: DMA stage 0 into buffer 0
#pragma unroll
    for (int i = 0; i < 4; ++i)
        gload_lds16(gk + tid + i * 256, (uint4*)kst[0] + tid + i * 256);
    if (tid < ST * 16) gload_lds4(gs + tid, &sst[0][tid]);

    for (int st = 0; st < NSTG; ++st) {
        int cur = st & 1;
        __syncthreads();   // drains DMA for buf[cur]; prev compute of buf[cur^1] done
        if (st + 1 < NSTG) {
#pragma unroll
            for (int i = 0; i < 4; ++i)
                gload_lds16(gk + (size_t)(st + 1) * 1024 + tid + i * 256,
                            (uint4*)kst[cur ^ 1] + tid + i * 256);
            if (tid < ST * 16)
                gload_lds4(gs + (st + 1) * ST * 16 + tid, &sst[cur ^ 1][tid]);
        }
        const ushort* kl = kst[cur] + lane * 8;
#pragma unroll
        for (int t = 0; t < ST; ++t) {
            short8 Bf[NC];
#pragma unroll
            for (int cb = 0; cb < NC; ++cb)
                Bf[cb] = *(const short8*)(kl + (t * NC + cb) * 512);
            float sv = sst[cur][t * 16 + cc];
            f32x4 c = {0.f, 0.f, 0.f, 0.f};
            if constexpr (D == 16) {
                c = __builtin_amdgcn_mfma_f32_16x16x32_bf16(Ah[0], Bf[1], c, 0, 0, 0);
                c = __builtin_amdgcn_mfma_f32_16x16x32_bf16(Ah[0], Bf[0], c, 0, 0, 0);
            } else {
#pragma unroll
                for (int h = 0; h < NF; ++h) {
                    c = __builtin_amdgcn_mfma_f32_16x16x32_bf16(Ah[h], Bf[h * 2 + 1], c, 0, 0, 0);
                    c = __builtin_amdgcn_mfma_f32_16x16x32_bf16(Al[h], Bf[h * 2], c, 0, 0, 0);
                    c = __builtin_amdgcn_mfma_f32_16x16x32_bf16(Al[h], Bf[h * 2 + 1], c, 0, 0, 0);
                    c = __builtin_amdgcn_mfma_f32_16x16x32_bf16(Ah[h], Bf[h * 2], c, 0, 0, 0);
                }
            }
#pragma unroll
            for (int r = 0; r < 4; ++r) {
                float e = __builtin_amdgcn_exp2f(c[r]);
                Sn[r] += e;
                Sw[r] += e * sv;
            }
        }
    }
#pragma unroll
    for (int mask = 1; mask < 16; mask <<= 1) {
#pragma unroll
        for (int r = 0; r < 4; ++r) {
            Sn[r] += __shfl_xor(Sn[r], mask, 64);
            Sw[r] += __shfl_xor(Sw[r], mask, 64);
        }
    }
    if (cc == 0) {
        int n = n0 + quad * 4;
        int pidx = (b * 4 + mc) * 4096 + n;
        *(float4*)&pSn[pidx] = make_float4(Sn[0], Sn[1], Sn[2], Sn[3]);
        *(float4*)&pSw[pidx] = make_float4(Sw[0], Sw[1], Sw[2], Sw[3]);
    }
}

// --------------------------- attn: all three scales ------------------------
__global__ __launch_bounds__(256) void attn_kernel(float* ws) {
    __shared__ __align__(16) ushort kst[2][8192];   // 2 x 16 KB stage buffers
    __shared__ float sst[2][128];
    int idx = blockIdx.x, tid = threadIdx.x;
    int li = idx & 1023;
    int nblk = li & 63, mc = (li >> 6) & 3, b = li >> 8;
    if (idx < 1024) {
        attn_mfma_body<64>((const ushort*)(ws + OFF_QP0), (const ushort*)(ws + OFF_KF0),
                           ws + OFF_SBIG0 + b * 4096,
                           ws + OFF_PSN0, ws + OFF_PSW0, nblk, mc, b, tid, kst, sst);
    } else if (idx < 2048) {
        attn_mfma_body<32>((const ushort*)(ws + OFF_QP1), (const ushort*)(ws + OFF_KF1),
                           ws + OFF_SBIG1 + b * 4096,
                           ws + OFF_PSN1, ws + OFF_PSW1, nblk, mc, b, tid, kst, sst);
    } else {
        attn_mfma_body<16>((const ushort*)(ws + OFF_QP2), (const ushort*)(ws + OFF_KF2),
                           ws + OFF_PROJ2 + ((size_t)b * 65 + 32) * 4096,
                           ws + OFF_PSN2, ws + OFF_PSW2, nblk, mc, b, tid, kst, sst);
    }
}

// --------------------------- final: combine + fusion -----------------------
__global__ __launch_bounds__(256) void final_kernel(const float* __restrict__ ws,
                                                    const float* __restrict__ ba0,
                                                    const float* __restrict__ ba1,
                                                    const float* __restrict__ ba2,
                                                    const float* __restrict__ b1,
                                                    const float* __restrict__ w2,
                                                    const float* __restrict__ b2,
                                                    float* __restrict__ out) {
    __shared__ float lb1[32], lw2[32];
    int tid = threadIdx.x;
    if (tid < 32) { lb1[tid] = b1[tid]; lw2[tid] = w2[tid]; }
    __syncthreads();
    int b = blockIdx.y;
    int n = blockIdx.x * 256 + tid;
    const float* pSns[3] = {ws + OFF_PSN0, ws + OFF_PSN1, ws + OFF_PSN2};
    const float* pSws[3] = {ws + OFF_PSW0, ws + OFF_PSW1, ws + OFF_PSW2};
    float aval[3];
#pragma unroll
    for (int s = 0; s < 3; ++s) {
        float Sn = 0.f, Sw = 0.f;
#pragma unroll
        for (int ch = 0; ch < 4; ++ch) {
            int pi = (b * 4 + ch) * 4096 + n;
            Sn += pSns[s][pi];
            Sw += pSws[s][pi];
        }
        float bav = (s == 0) ? ba0[0] : (s == 1) ? ba1[0] : ba2[0];
        aval[s] = Sw / Sn + bav;
    }
    float prod = aval[0] * aval[1] * aval[2];
    int oy = n >> 6, ox = n & 63;
    float f0 = 15.0f / 63.0f;
    float cy0 = oy * f0, cx0 = ox * f0;
    int iy0 = min((int)cy0, 14), ix0 = min((int)cx0, 14);
    float wy0 = cy0 - iy0, wx0 = cx0 - ix0;
    float f1 = 31.0f / 63.0f;
    float cy1 = oy * f1, cx1 = ox * f1;
    int iy1 = min((int)cy1, 30), ix1 = min((int)cx1, 30);
    float wy1 = cy1 - iy1, wx1 = cx1 - ix1;
    const float* g0b = ws + OFF_PROJ0 + (b * 161 + 129) * 256;
    const float* g1b = ws + OFF_PROJ1 + (b * 97 + 65) * 1024;
    const float* g2b = ws + OFF_PROJ2 + (b * 65 + 33) * 4096;
    float outv = 0.f;
#pragma unroll 4
    for (int j = 0; j < 32; ++j) {
        const float* p0 = g0b + j * 256;
        float v0 = (1.f - wy0) * ((1.f - wx0) * p0[iy0 * 16 + ix0] + wx0 * p0[iy0 * 16 + ix0 + 1]) +
                   wy0 * ((1.f - wx0) * p0[(iy0 + 1) * 16 + ix0] + wx0 * p0[(iy0 + 1) * 16 + ix0 + 1]);
        const float* p1 = g1b + j * 1024;
        float v1 = (1.f - wy1) * ((1.f - wx1) * p1[iy1 * 32 + ix1] + wx1 * p1[iy1 * 32 + ix1 + 1]) +
                   wy1 * ((1.f - wx1) * p1[(iy1 + 1) * 32 + ix1] + wx1 * p1[(iy1 + 1) * 32 + ix1 + 1]);
        float g = g2b[j * 4096 + n] + v0 + v1;
        float h = fmaxf(prod * g + lb1[j], 0.f);
        outv += lw2[j] * h;
    }
    out[b * 4096 + n] = outv + b2[0];
}

// ---------------------------------------------------------------------------
extern "C" void kernel_launch(void* const* d_in, const int* in_sizes, int n_in,
                              void* d_out, int out_size, void* d_ws, size_t ws_size,
                              hipStream_t stream) {
    const float* x3 = (const float*)d_in[0];
    const float* x2 = (const float*)d_in[1];
    const float* x1 = (const float*)d_in[2];
    const float* W[24];
    for (int i = 0; i < 24; ++i) W[i] = (const float*)d_in[3 + i];
    const float* w1 = (const float*)d_in[27];
    const float* b1 = (const float*)d_in[28];
    const float* w2 = (const float*)d_in[29];
    const float* b2 = (const float*)d_in[30];
    float* ws = (float*)d_ws;
    float* out = (float*)d_out;

    UArgs ua;
    ua.wv0 = W[4];  ua.wa0 = W[6];  ua.bv0 = W[5];
    ua.wv1 = W[12]; ua.wa1 = W[14]; ua.bv1 = W[13];
    ua.wv2 = W[20]; ua.wa2 = W[22]; ua.bv2 = W[21];
    ua.ws = ws;
    u_kernel<<<56, 256, 0, stream>>>(ua);

    ProjArgs ja;
    ja.x0 = x1; ja.x1 = x2; ja.x2 = x3;
    ja.wq0 = W[0];  ja.wk0 = W[2];  ja.bq0 = W[1];  ja.bk0 = W[3];
    ja.wq1 = W[8];  ja.wk1 = W[10]; ja.bq1 = W[9];  ja.bk1 = W[11];
    ja.wq2 = W[16]; ja.wk2 = W[18]; ja.bq2 = W[17]; ja.bk2 = W[19];
    ja.w1 = w1; ja.ws = ws;
    proj_kernel<<<952, 256, 0, stream>>>(ja);

    mid_kernel<<<640, 256, 0, stream>>>(ws);

    attn_kernel<<<3072, 256, 0, stream>>>(ws);

    final_kernel<<<dim3(16, BB), 256, 0, stream>>>(ws, W[7], W[15], W[23],
                                                   b1, w2, b2, out);
}

// Round 10
// 260.360 us; speedup vs baseline: 1.1824x; 1.1824x over previous
//
#include <hip/hip_runtime.h>

// ---------------------------------------------------------------------------
// MultiScaleFeatureFusion — R25 (= R24 + "#pragma unroll 1" on stage loop).
//   scale0: x1 [4,512,16,16]  d=64 C=512 hs=16 Ns=256  R=161
//   scale1: x2 [4,256,32,32]  d=32 C=256 hs=32 Ns=1024 R=97
//   scale2: x3 [4,128,64,64]  d=16 C=128 hs=64 Ns=4096 R=65
// attn: k/s staged via __builtin_amdgcn_global_load_lds (direct global->LDS
// DMA, no staging VGPRs) into a double buffer: DMA for stage s+1 issues
// right after the stage-s barrier and lands during stage-s compute -> ONE
// barrier per stage, per-stage L2 latency hidden.
// R24 BUG: the stage loop (constexpr trip count) was fully unrolled ->
// all 16 stages' DMA addresses live at once -> VGPR 216, occupancy 11%,
// 133us. "#pragma unroll 1" keeps per-iteration addressing (~48-64 VGPR).
// Compute order bit-identical to R16/R23.
// ---------------------------------------------------------------------------

#define BB 4
#define LOG2E 1.44269504088896340736f

typedef __attribute__((ext_vector_type(8))) short short8;
typedef __attribute__((ext_vector_type(4))) float f32x4;

static constexpr int OFF_UP0 = 0;                        // [4][512]
static constexpr int OFF_UP1 = OFF_UP0 + 4 * 512;
static constexpr int OFF_UP2 = OFF_UP1 + 4 * 256;
static constexpr int OFF_UB0 = OFF_UP2 + 4 * 128;
static constexpr int OFF_UB1 = OFF_UB0 + 4;
static constexpr int OFF_UB2 = OFF_UB1 + 4;
static constexpr int OFF_PROJ0 = OFF_UB2 + 4;
static constexpr int OFF_PROJ1 = OFF_PROJ0 + BB * 161 * 256;
static constexpr int OFF_PROJ2 = OFF_PROJ1 + BB * 97 * 1024;
static constexpr int OFF_SBIG0 = OFF_PROJ2 + BB * 65 * 4096;   // [b][4096]
static constexpr int OFF_SBIG1 = OFF_SBIG0 + BB * 4096;        // [b][4096]
static constexpr int OFF_QP0 = OFF_SBIG1 + BB * 4096;          // BB*4096*64 fl
static constexpr int OFF_KF0 = OFF_QP0 + BB * 4096 * 64;       // BB*262144 fl
static constexpr int OFF_QP1 = OFF_KF0 + BB * 262144;          // BB*4096*32 fl
static constexpr int OFF_KF1 = OFF_QP1 + BB * 4096 * 32;       // BB*131072 fl
static constexpr int OFF_QP2 = OFF_KF1 + BB * 131072;          // BB*4096*16 fl
static constexpr int OFF_KF2 = OFF_QP2 + BB * 4096 * 16;       // BB*131072 fl
static constexpr int PS = BB * 4 * 4096;
static constexpr int OFF_PSN0 = OFF_KF2 + BB * 131072;
static constexpr int OFF_PSW0 = OFF_PSN0 + PS;
static constexpr int OFF_PSN1 = OFF_PSW0 + PS;
static constexpr int OFF_PSW1 = OFF_PSN1 + PS;
static constexpr int OFF_PSN2 = OFF_PSW1 + PS;
static constexpr int OFF_PSW2 = OFF_PSN2 + PS;

// ---- direct global->LDS DMA helpers (size literal; dest = base+lane*sz) ---
__device__ inline void gload_lds16(const void* g, void* l) {
    __builtin_amdgcn_global_load_lds((const __attribute__((address_space(1))) void*)g,
                                     (__attribute__((address_space(3))) void*)l, 16, 0, 0);
}
__device__ inline void gload_lds4(const void* g, void* l) {
    __builtin_amdgcn_global_load_lds((const __attribute__((address_space(1))) void*)g,
                                     (__attribute__((address_space(3))) void*)l, 4, 0, 0);
}

// --------------------------- u partials ------------------------------------
struct UArgs {
    const float *wv0, *wa0, *bv0;
    const float *wv1, *wa1, *bv1;
    const float *wv2, *wa2, *bv2;
    float* ws;
};

__global__ void u_kernel(UArgs A) {
    __shared__ float red[256];
    int idx = blockIdx.x, tid = threadIdx.x;
    int C, cit, chunk;
    const float *wv, *wa, *bv;
    float *up, *ub;
    if (idx < 32) {
        C = 512; cit = idx >> 2; chunk = idx & 3;
        wv = A.wv0; wa = A.wa0; bv = A.bv0;
        up = A.ws + OFF_UP0; ub = A.ws + OFF_UB0;
    } else if (idx < 48) {
        int i2 = idx - 32;
        C = 256; cit = i2 >> 2; chunk = i2 & 3;
        wv = A.wv1; wa = A.wa1; bv = A.bv1;
        up = A.ws + OFF_UP1; ub = A.ws + OFF_UB1;
    } else {
        int i2 = idx - 48;
        C = 128; cit = i2 >> 2; chunk = i2 & 3;
        wv = A.wv2; wa = A.wa2; bv = A.bv2;
        up = A.ws + OFF_UP2; ub = A.ws + OFF_UB2;
    }
    int lci = tid & 63, sub = tid >> 6;
    int ci = cit * 64 + lci;
    int coBeg = chunk * (C >> 2), coEnd = coBeg + (C >> 2);
    float acc = 0.f;
#pragma unroll 4
    for (int co = coBeg + sub; co < coEnd; co += 4)
        acc += wa[co] * wv[(size_t)co * C + ci];
    red[tid] = acc;
    __syncthreads();
    if (sub == 0)
        up[chunk * C + ci] = red[lci] + red[lci + 64] + red[lci + 128] + red[lci + 192];
    if (cit == 0) {
        __syncthreads();
        float bacc = 0.f;
        for (int co = coBeg + tid; co < coEnd; co += 256) bacc += wa[co] * bv[co];
        red[tid] = bacc;
        __syncthreads();
        for (int off = 128; off > 0; off >>= 1) {
            if (tid < off) red[tid] += red[tid + off];
            __syncthreads();
        }
        if (tid == 0) ub[chunk] = red[0];
    }
}

// --------------------------- proj: all scales, 16 rows/block, 2 m/thread ---
struct ProjArgs {
    const float *x0, *x1, *x2;
    const float *wq0, *wk0, *bq0, *bk0;
    const float *wq1, *wk1, *bq1, *bk1;
    const float *wq2, *wk2, *bq2, *bk2;
    const float *w1;
    float* ws;
};

__global__ __launch_bounds__(256) void proj_kernel(ProjArgs A) {
    __shared__ __align__(16) float Wl[512 * 16];  // [c][rr]
    __shared__ float bl[16];
    __shared__ float red[2048];
    int idx = blockIdx.x, tid = threadIdx.x;
    const float *x, *wq, *wk, *bq, *bk, *up, *ub;
    float* out;
    int C, Ns, R, nx, d, w1off, local;
    if (idx < 88) {
        local = idx; x = A.x0; out = A.ws + OFF_PROJ0;
        wq = A.wq0; wk = A.wk0; bq = A.bq0; bk = A.bk0;
        up = A.ws + OFF_UP0; ub = A.ws + OFF_UB0;
        C = 512; Ns = 256; R = 161; nx = 2; d = 64; w1off = 384;
    } else if (idx < 312) {
        local = idx - 88; x = A.x1; out = A.ws + OFF_PROJ1;
        wq = A.wq1; wk = A.wk1; bq = A.bq1; bk = A.bk1;
        up = A.ws + OFF_UP1; ub = A.ws + OFF_UB1;
        C = 256; Ns = 1024; R = 97; nx = 8; d = 32; w1off = 128;
    } else {
        local = idx - 312; x = A.x2; out = A.ws + OFF_PROJ2;
        wq = A.wq2; wk = A.wk2; bq = A.bq2; bk = A.bk2;
        up = A.ws + OFF_UP2; ub = A.ws + OFF_UB2;
        C = 128; Ns = 4096; R = 65; nx = 32; d = 16; w1off = 0;
    }
    int ny = (R + 15) >> 4;
    int pb = nx * ny;
    int b = local / pb;
    int rem = local - b * pb;
    int by = rem / nx;
    int bx = rem - by * nx;
    int r0 = by * 16;
    int nr = min(16, R - r0);
    for (int rp = 0; rp < 16; rp += 8) {
        int rr = rp + (tid >> 5), cg = tid & 31;
        int gr = r0 + rr;
        if (gr == 2 * d) {
            for (int c = cg; c < C; c += 32)
                Wl[c * 16 + rr] = up[c] + up[C + c] + up[2 * C + c] + up[3 * C + c];
        } else {
            const float* rowsrc;
            if (gr < d) rowsrc = wq + (size_t)gr * C;
            else if (gr < 2 * d) rowsrc = wk + (size_t)(gr - d) * C;
            else if (gr < R) rowsrc = A.w1 + (size_t)(gr - 2 * d - 1) * 896 + w1off;
            else rowsrc = nullptr;
            if (rowsrc) {
                for (int c = cg; c < C; c += 32) Wl[c * 16 + rr] = rowsrc[c];
            } else {
                for (int c = cg; c < C; c += 32) Wl[c * 16 + rr] = 0.f;
            }
        }
    }
    if (tid < 16) {
        int g2 = r0 + tid;
        float bv2;
        if (g2 < d) bv2 = bq[g2];
        else if (g2 < 2 * d) bv2 = bk[g2 - d];
        else if (g2 == 2 * d) bv2 = ub[0] + ub[1] + ub[2] + ub[3];
        else bv2 = 0.f;
        bl[tid] = bv2;
    }
    __syncthreads();
    int lane = tid & 63, strip = tid >> 6;
    int m0 = bx * 128 + lane * 2;
    const float* xb = x + (size_t)(b * C) * Ns + m0;
    float acc[16][2];
#pragma unroll
    for (int r = 0; r < 16; ++r) {
        acc[r][0] = 0.f;
        acc[r][1] = 0.f;
    }
    float2 buf[4];
#pragma unroll
    for (int j = 0; j < 4; ++j)
        buf[j] = *(const float2*)&xb[(size_t)(strip + 4 * j) * Ns];
    for (int c0 = strip; c0 < C; c0 += 16) {
#pragma unroll
        for (int j = 0; j < 4; ++j) {
            int c = c0 + 4 * j;
            float2 xv = buf[j];
            int cn = c + 16;
            if (cn < C) buf[j] = *(const float2*)&xb[(size_t)cn * Ns];
            const float* wl = &Wl[c * 16];
#pragma unroll
            for (int r4 = 0; r4 < 4; ++r4) {
                float4 w = *(const float4*)&wl[r4 * 4];
                acc[r4 * 4 + 0][0] += w.x * xv.x; acc[r4 * 4 + 0][1] += w.x * xv.y;
                acc[r4 * 4 + 1][0] += w.y * xv.x; acc[r4 * 4 + 1][1] += w.y * xv.y;
                acc[r4 * 4 + 2][0] += w.z * xv.x; acc[r4 * 4 + 2][1] += w.z * xv.y;
                acc[r4 * 4 + 3][0] += w.w * xv.x; acc[r4 * 4 + 3][1] += w.w * xv.y;
            }
        }
    }
    for (int rp = 0; rp < 16; rp += 4) {
        __syncthreads();
#pragma unroll
        for (int r = 0; r < 4; ++r)
#pragma unroll
            for (int j = 0; j < 2; ++j)
                red[((r * 2 + j) * 4 + strip) * 64 + lane] = acc[rp + r][j];
        __syncthreads();
        int g = tid >> 6;
        int rr2 = rp + g;
        if (rr2 < nr) {
            float v[2];
#pragma unroll
            for (int j = 0; j < 2; ++j) {
                int base = (g * 2 + j) * 256 + lane;
                v[j] = red[base] + red[base + 64] + red[base + 128] + red[base + 192] + bl[rr2];
            }
            float2 v2; v2.x = v[0]; v2.y = v[1];
            *(float2*)&out[(size_t)(b * R + r0 + rr2) * Ns + m0] = v2;
        }
    }
}

// --------------------------- hi/lo split helper ----------------------------
__device__ inline void split_bf16(float f, ushort& hi, ushort& lo) {
    unsigned u = __float_as_uint(f);
    unsigned h = u >> 16;
    float r = f - __uint_as_float(h << 16);
    hi = (ushort)h;
    lo = (ushort)(__float_as_uint(r) >> 16);
}

// --------------------------- bilerp field values ---------------------------
template <int D, int HS>
__device__ void bilerp_vals(const float* __restrict__ proj, int R, int rowbase,
                            float scale, int b, int n, float* vals) {
    constexpr int NS = HS * HS;
    constexpr float f = (float)(HS - 1) / 63.0f;
    int oy = n >> 6, ox = n & 63;
    float cy = oy * f, cx = ox * f;
    int iy0 = min((int)cy, HS - 2);
    int ix0 = min((int)cx, HS - 2);
    float wy = cy - iy0, wx = cx - ix0;
    float w00 = (1.f - wy) * (1.f - wx) * scale, w01 = (1.f - wy) * wx * scale;
    float w10 = wy * (1.f - wx) * scale, w11 = wy * wx * scale;
    const float* pb = proj + ((size_t)b * R + rowbase) * NS + iy0 * HS + ix0;
#pragma unroll
    for (int d = 0; d < D; ++d) {
        const float* p = pb + (size_t)d * NS;
        vals[d] = w00 * p[0] + w01 * p[1] + w10 * p[HS] + w11 * p[HS + 1];
    }
}

// --------------------------- q pack ([n][2D] layout) -----------------------
template <int D>
__device__ void q_store(ushort* __restrict__ dst, const float* vals, int b, int n) {
    ushort outv[2 * D];
#pragma unroll
    for (int d = 0; d < D; ++d) split_bf16(vals[d], outv[d], outv[D + d]);
    ushort* dp = dst + (size_t)(b * 4096 + n) * (2 * D);
#pragma unroll
    for (int i = 0; i < D / 4; ++i)
        ((uint4*)dp)[i] = ((const uint4*)outv)[i];
}

// q pack for scale0, one 32-field chunk (chunk 0: d 0..31, chunk 1: 32..63).
__device__ void q_store_c32(ushort* __restrict__ dst, const float* vals,
                            int b, int n, int chunk) {
    ushort outv[64];
#pragma unroll
    for (int d = 0; d < 32; ++d) split_bf16(vals[d], outv[d], outv[32 + d]);
    ushort* dp = dst + (size_t)(b * 4096 + n) * 128;
#pragma unroll
    for (int i = 0; i < 4; ++i)
        ((uint4*)dp)[chunk * 4 + i] = ((const uint4*)outv)[i];
#pragma unroll
    for (int i = 0; i < 4; ++i)
        ((uint4*)dp)[8 + chunk * 4 + i] = ((const uint4*)outv)[4 + i];
}

// --------------------------- k pack (fragment order) -----------------------
template <int D>
__device__ void k_store(ushort* __restrict__ dst, const float* vals, int b, int n) {
    constexpr int NC = (D == 16) ? 2 : (D / 32) * 2;
    ushort hi[D], lo[D];
#pragma unroll
    for (int d = 0; d < D; ++d) split_bf16(vals[d], hi[d], lo[d]);
    int tile = n >> 4, cc = n & 15;
    ushort* kb = dst + (size_t)b * (256 * NC * 512) + (size_t)tile * (NC * 512);
    if constexpr (D == 16) {
#pragma unroll
        for (int combo = 0; combo < 2; ++combo)
#pragma unroll
            for (int quad = 0; quad < 4; ++quad) {
                const ushort* src = (combo == 0 ? hi : lo) + (quad & 1) * 8;
                ushort* dp = kb + ((size_t)combo * 512 + (quad * 16 + cc) * 8);
                *(uint4*)dp = *(const uint4*)src;
            }
    } else {
#pragma unroll
        for (int h = 0; h < D / 32; ++h)
#pragma unroll
            for (int part = 0; part < 2; ++part) {
                int combo = h * 2 + part;
#pragma unroll
                for (int quad = 0; quad < 4; ++quad) {
                    const ushort* src = (part == 0 ? hi : lo) + h * 32 + quad * 8;
                    ushort* dp = kb + ((size_t)combo * 512 + (quad * 16 + cc) * 8);
                    *(uint4*)dp = *(const uint4*)src;
                }
            }
    }
}

// k pack for scale0, one 32-field chunk (h = chunk): writes combos
// {chunk*2, chunk*2+1} — disjoint across chunks, bit-identical union.
__device__ void k_store_c32(ushort* __restrict__ dst, const float* vals,
                            int b, int n, int chunk) {
    ushort hi[32], lo[32];
#pragma unroll
    for (int d = 0; d < 32; ++d) split_bf16(vals[d], hi[d], lo[d]);
    int tile = n >> 4, cc = n & 15;
    ushort* kb = dst + (size_t)b * (256 * 4 * 512) + (size_t)tile * (4 * 512);
#pragma unroll
    for (int part = 0; part < 2; ++part) {
        int combo = chunk * 2 + part;
#pragma unroll
        for (int quad = 0; quad < 4; ++quad) {
            const ushort* src = (part == 0 ? hi : lo) + quad * 8;
            ushort* dp = kb + ((size_t)combo * 512 + (quad * 16 + cc) * 8);
            *(uint4*)dp = *(const uint4*)src;
        }
    }
}

// --------------------------- native field values (scale2) ------------------
__device__ void nat_vals(const float* __restrict__ proj, int rowbase, float scale,
                         int b, int n, float* vals) {
    const float* pb = proj + ((size_t)b * 65 + rowbase) * 4096 + n;
#pragma unroll
    for (int d = 0; d < 16; ++d) vals[d] = pb[(size_t)d * 4096] * scale;
}

// --------------------------- mid: upsample-s + packs -----------------------
__global__ __launch_bounds__(256) void mid_kernel(float* ws) {
    int idx = blockIdx.x, tid = threadIdx.x;
    if (idx < 128) {
        int gi = idx * 256 + tid;
        int seg = gi >> 14;
        int li = gi & 16383;
        int b = li >> 12, n = li & 4095;
        const float* src;
        float* dst;
        int hs;
        if (seg == 0) { src = ws + OFF_PROJ0 + (b * 161 + 128) * 256;  dst = ws + OFF_SBIG0; hs = 16; }
        else          { src = ws + OFF_PROJ1 + (b * 97 + 64) * 1024;   dst = ws + OFF_SBIG1; hs = 32; }
        int oy = n >> 6, ox = n & 63;
        float f = (float)(hs - 1) / 63.0f;
        float cy = oy * f, cx = ox * f;
        int iy0 = min((int)cy, hs - 2);
        int ix0 = min((int)cx, hs - 2);
        float wy = cy - iy0, wx = cx - ix0;
        float v00 = src[iy0 * hs + ix0], v01 = src[iy0 * hs + ix0 + 1];
        float v10 = src[(iy0 + 1) * hs + ix0], v11 = src[(iy0 + 1) * hs + ix0 + 1];
        float t0 = v00 + wx * (v01 - v00), t1 = v10 + wx * (v11 - v10);
        dst[b * 4096 + n] = t0 + wy * (t1 - t0);
    } else if (idx < 384) {
        int li = idx - 128;               // 0..255: scale0, 2 chunks
        int field = li >> 7;
        int rest = li & 127;
        int b = rest >> 5;
        int nt = (rest >> 1) & 15;
        int chunk = rest & 1;
        int n = nt * 256 + tid;
        float vals[32];
        if (field == 0) {
            bilerp_vals<32, 16>(ws + OFF_PROJ0, 161, chunk * 32, LOG2E, b, n, vals);
            q_store_c32((ushort*)(ws + OFF_QP0), vals, b, n, chunk);
        } else {
            bilerp_vals<32, 16>(ws + OFF_PROJ0, 161, 64 + chunk * 32, 1.0f, b, n, vals);
            k_store_c32((ushort*)(ws + OFF_KF0), vals, b, n, chunk);
        }
    } else if (idx < 512) {
        int li = idx - 384;
        int field = li >> 6, b = (li >> 4) & 3, nt = li & 15;
        int n = nt * 256 + tid;
        float vals[32];
        if (field == 0) {
            bilerp_vals<32, 32>(ws + OFF_PROJ1, 97, 0, LOG2E, b, n, vals);
            q_store<32>((ushort*)(ws + OFF_QP1), vals, b, n);
        } else {
            bilerp_vals<32, 32>(ws + OFF_PROJ1, 97, 32, 1.0f, b, n, vals);
            k_store<32>((ushort*)(ws + OFF_KF1), vals, b, n);
        }
    } else {
        int li = idx - 512;
        int field = li >> 6, b = (li >> 4) & 3, nt = li & 15;
        int n = nt * 256 + tid;
        float vals[16];
        if (field == 0) {
            nat_vals(ws + OFF_PROJ2, 0, LOG2E, b, n, vals);
            q_store<16>((ushort*)(ws + OFF_QP2), vals, b, n);
        } else {
            nat_vals(ws + OFF_PROJ2, 16, 1.0f, b, n, vals);
            k_store<16>((ushort*)(ws + OFF_KF2), vals, b, n);
        }
    }
}

// --------------------------- MFMA attention body ---------------------------
// Double-buffered DMA staging: global_load_lds issues stage s+1's k/s loads
// right after the stage-s barrier; they land in LDS buf[cur^1] during
// stage-s compute. ONE barrier per stage. Zero staging VGPRs. The stage
// loop MUST NOT be unrolled (R24: full unroll -> 216 VGPR, occ 11%).
// Per-element MFMA/exp/accumulation order identical to R16 (bit-exact).
template <int D>
__device__ void attn_mfma_body(const ushort* __restrict__ qp, const ushort* __restrict__ kf,
                               const float* __restrict__ srow,
                               float* __restrict__ pSn, float* __restrict__ pSw,
                               int nblk, int mc, int b, int tid,
                               ushort (*kst)[8192], float (*sst)[128]) {
    constexpr int NC = (D == 16) ? 2 : (D / 32) * 2;
    constexpr int ST = 16 / NC;       // tiles per stage (stage = 16 KB)
    constexpr int NF = (D >= 32) ? (D / 32) : 1;
    constexpr int NSTG = 64 / ST;     // stages per 1024-m chunk
    int wave = tid >> 6, lane = tid & 63;
    int cc = lane & 15, quad = lane >> 4;
    int n0 = (nblk * 4 + wave) * 16;
    const ushort* qn = qp + (size_t)(b * 4096 + n0 + cc) * (2 * D);
    short8 Ah[NF], Al[NF];
    if constexpr (D == 16) {
        Ah[0] = *(const short8*)(qn + quad * 8);   // [qh16|ql16] spans k=0..31
    } else {
#pragma unroll
        for (int h = 0; h < NF; ++h) {
            Ah[h] = *(const short8*)(qn + h * 32 + quad * 8);
            Al[h] = *(const short8*)(qn + D + h * 32 + quad * 8);
        }
    }
    float Sn[4] = {0.f, 0.f, 0.f, 0.f};
    float Sw[4] = {0.f, 0.f, 0.f, 0.f};
    int tbase = mc * 64;
    const uint4* gk = (const uint4*)(kf + (size_t)b * (256 * NC * 512) +
                                     (size_t)tbase * (NC * 512));
    const float* gs = srow + tbase * 16;

    // prologue: DMA stage 0 into buffer 0
#pragma unroll
    for (int i = 0; i < 4; ++i)
        gload_lds16(gk + tid + i * 256, (uint4*)kst[0] + tid + i * 256);
    if (tid < ST * 16) gload_lds4(gs + tid, &sst[0][tid]);

#pragma unroll 1
    for (int st = 0; st < NSTG; ++st) {
        int cur = st & 1;
        __syncthreads();   // drains DMA for buf[cur]; prev compute of buf[cur^1] done
        if (st + 1 < NSTG) {
#pragma unroll
            for (int i = 0; i < 4; ++i)
                gload_lds16(gk + (size_t)(st + 1) * 1024 + tid + i * 256,
                            (uint4*)kst[cur ^ 1] + tid + i * 256);
            if (tid < ST * 16)
                gload_lds4(gs + (st + 1) * ST * 16 + tid, &sst[cur ^ 1][tid]);
        }
        const ushort* kl = kst[cur] + lane * 8;
#pragma unroll
        for (int t = 0; t < ST; ++t) {
            short8 Bf[NC];
#pragma unroll
            for (int cb = 0; cb < NC; ++cb)
                Bf[cb] = *(const short8*)(kl + (t * NC + cb) * 512);
            float sv = sst[cur][t * 16 + cc];
            f32x4 c = {0.f, 0.f, 0.f, 0.f};
            if constexpr (D == 16) {
                c = __builtin_amdgcn_mfma_f32_16x16x32_bf16(Ah[0], Bf[1], c, 0, 0, 0);
                c = __builtin_amdgcn_mfma_f32_16x16x32_bf16(Ah[0], Bf[0], c, 0, 0, 0);
            } else {
#pragma unroll
                for (int h = 0; h < NF; ++h) {
                    c = __builtin_amdgcn_mfma_f32_16x16x32_bf16(Ah[h], Bf[h * 2 + 1], c, 0, 0, 0);
                    c = __builtin_amdgcn_mfma_f32_16x16x32_bf16(Al[h], Bf[h * 2], c, 0, 0, 0);
                    c = __builtin_amdgcn_mfma_f32_16x16x32_bf16(Al[h], Bf[h * 2 + 1], c, 0, 0, 0);
                    c = __builtin_amdgcn_mfma_f32_16x16x32_bf16(Ah[h], Bf[h * 2], c, 0, 0, 0);
                }
            }
#pragma unroll
            for (int r = 0; r < 4; ++r) {
                float e = __builtin_amdgcn_exp2f(c[r]);
                Sn[r] += e;
                Sw[r] += e * sv;
            }
        }
    }
#pragma unroll
    for (int mask = 1; mask < 16; mask <<= 1) {
#pragma unroll
        for (int r = 0; r < 4; ++r) {
            Sn[r] += __shfl_xor(Sn[r], mask, 64);
            Sw[r] += __shfl_xor(Sw[r], mask, 64);
        }
    }
    if (cc == 0) {
        int n = n0 + quad * 4;
        int pidx = (b * 4 + mc) * 4096 + n;
        *(float4*)&pSn[pidx] = make_float4(Sn[0], Sn[1], Sn[2], Sn[3]);
        *(float4*)&pSw[pidx] = make_float4(Sw[0], Sw[1], Sw[2], Sw[3]);
    }
}

// --------------------------- attn: all three scales ------------------------
__global__ __launch_bounds__(256) void attn_kernel(float* ws) {
    __shared__ __align__(16) ushort kst[2][8192];   // 2 x 16 KB stage buffers
    __shared__ float sst[2][128];
    int idx = blockIdx.x, tid = threadIdx.x;
    int li = idx & 1023;
    int nblk = li & 63, mc = (li >> 6) & 3, b = li >> 8;
    if (idx < 1024) {
        attn_mfma_body<64>((const ushort*)(ws + OFF_QP0), (const ushort*)(ws + OFF_KF0),
                           ws + OFF_SBIG0 + b * 4096,
                           ws + OFF_PSN0, ws + OFF_PSW0, nblk, mc, b, tid, kst, sst);
    } else if (idx < 2048) {
        attn_mfma_body<32>((const ushort*)(ws + OFF_QP1), (const ushort*)(ws + OFF_KF1),
                           ws + OFF_SBIG1 + b * 4096,
                           ws + OFF_PSN1, ws + OFF_PSW1, nblk, mc, b, tid, kst, sst);
    } else {
        attn_mfma_body<16>((const ushort*)(ws + OFF_QP2), (const ushort*)(ws + OFF_KF2),
                           ws + OFF_PROJ2 + ((size_t)b * 65 + 32) * 4096,
                           ws + OFF_PSN2, ws + OFF_PSW2, nblk, mc, b, tid, kst, sst);
    }
}

// --------------------------- final: combine + fusion -----------------------
__global__ __launch_bounds__(256) void final_kernel(const float* __restrict__ ws,
                                                    const float* __restrict__ ba0,
                                                    const float* __restrict__ ba1,
                                                    const float* __restrict__ ba2,
                                                    const float* __restrict__ b1,
                                                    const float* __restrict__ w2,
                                                    const float* __restrict__ b2,
                                                    float* __restrict__ out) {
    __shared__ float lb1[32], lw2[32];
    int tid = threadIdx.x;
    if (tid < 32) { lb1[tid] = b1[tid]; lw2[tid] = w2[tid]; }
    __syncthreads();
    int b = blockIdx.y;
    int n = blockIdx.x * 256 + tid;
    const float* pSns[3] = {ws + OFF_PSN0, ws + OFF_PSN1, ws + OFF_PSN2};
    const float* pSws[3] = {ws + OFF_PSW0, ws + OFF_PSW1, ws + OFF_PSW2};
    float aval[3];
#pragma unroll
    for (int s = 0; s < 3; ++s) {
        float Sn = 0.f, Sw = 0.f;
#pragma unroll
        for (int ch = 0; ch < 4; ++ch) {
            int pi = (b * 4 + ch) * 4096 + n;
            Sn += pSns[s][pi];
            Sw += pSws[s][pi];
        }
        float bav = (s == 0) ? ba0[0] : (s == 1) ? ba1[0] : ba2[0];
        aval[s] = Sw / Sn + bav;
    }
    float prod = aval[0] * aval[1] * aval[2];
    int oy = n >> 6, ox = n & 63;
    float f0 = 15.0f / 63.0f;
    float cy0 = oy * f0, cx0 = ox * f0;
    int iy0 = min((int)cy0, 14), ix0 = min((int)cx0, 14);
    float wy0 = cy0 - iy0, wx0 = cx0 - ix0;
    float f1 = 31.0f / 63.0f;
    float cy1 = oy * f1, cx1 = ox * f1;
    int iy1 = min((int)cy1, 30), ix1 = min((int)cx1, 30);
    float wy1 = cy1 - iy1, wx1 = cx1 - ix1;
    const float* g0b = ws + OFF_PROJ0 + (b * 161 + 129) * 256;
    const float* g1b = ws + OFF_PROJ1 + (b * 97 + 65) * 1024;
    const float* g2b = ws + OFF_PROJ2 + (b * 65 + 33) * 4096;
    float outv = 0.f;
#pragma unroll 4
    for (int j = 0; j < 32; ++j) {
        const float* p0 = g0b + j * 256;
        float v0 = (1.f - wy0) * ((1.f - wx0) * p0[iy0 * 16 + ix0] + wx0 * p0[iy0 * 16 + ix0 + 1]) +
                   wy0 * ((1.f - wx0) * p0[(iy0 + 1) * 16 + ix0] + wx0 * p0[(iy0 + 1) * 16 + ix0 + 1]);
        const float* p1 = g1b + j * 1024;
        float v1 = (1.f - wy1) * ((1.f - wx1) * p1[iy1 * 32 + ix1] + wx1 * p1[iy1 * 32 + ix1 + 1]) +
                   wy1 * ((1.f - wx1) * p1[(iy1 + 1) * 32 + ix1] + wx1 * p1[(iy1 + 1) * 32 + ix1 + 1]);
        float g = g2b[j * 4096 + n] + v0 + v1;
        float h = fmaxf(prod * g + lb1[j], 0.f);
        outv += lw2[j] * h;
    }
    out[b * 4096 + n] = outv + b2[0];
}

// ---------------------------------------------------------------------------
extern "C" void kernel_launch(void* const* d_in, const int* in_sizes, int n_in,
                              void* d_out, int out_size, void* d_ws, size_t ws_size,
                              hipStream_t stream) {
    const float* x3 = (const float*)d_in[0];
    const float* x2 = (const float*)d_in[1];
    const float* x1 = (const float*)d_in[2];
    const float* W[24];
    for (int i = 0; i < 24; ++i) W[i] = (const float*)d_in[3 + i];
    const float* w1 = (const float*)d_in[27];
    const float* b1 = (const float*)d_in[28];
    const float* w2 = (const float*)d_in[29];
    const float* b2 = (const float*)d_in[30];
    float* ws = (float*)d_ws;
    float* out = (float*)d_out;

    UArgs ua;
    ua.wv0 = W[4];  ua.wa0 = W[6];  ua.bv0 = W[5];
    ua.wv1 = W[12]; ua.wa1 = W[14]; ua.bv1 = W[13];
    ua.wv2 = W[20]; ua.wa2 = W[22]; ua.bv2 = W[21];
    ua.ws = ws;
    u_kernel<<<56, 256, 0, stream>>>(ua);

    ProjArgs ja;
    ja.x0 = x1; ja.x1 = x2; ja.x2 = x3;
    ja.wq0 = W[0];  ja.wk0 = W[2];  ja.bq0 = W[1];  ja.bk0 = W[3];
    ja.wq1 = W[8];  ja.wk1 = W[10]; ja.bq1 = W[9];  ja.bk1 = W[11];
    ja.wq2 = W[16]; ja.wk2 = W[18]; ja.bq2 = W[17]; ja.bk2 = W[19];
    ja.w1 = w1; ja.ws = ws;
    proj_kernel<<<952, 256, 0, stream>>>(ja);

    mid_kernel<<<640, 256, 0, stream>>>(ws);

    attn_kernel<<<3072, 256, 0, stream>>>(ws);

    final_kernel<<<dim3(16, BB), 256, 0, stream>>>(ws, W[7], W[15], W[23],
                                                   b1, w2, b2, out);
}

// Round 11
// 258.369 us; speedup vs baseline: 1.1915x; 1.0077x over previous
//
#include <hip/hip_runtime.h>

// ---------------------------------------------------------------------------
// MultiScaleFeatureFusion — R26 (= R25 with attn split into per-scale
// kernels attn0/attn1/attn2 — DIAGNOSTIC: surfaces the other kernels'
// durations in rocprof top-5; bodies byte-identical to R25's template
// instantiations, so the split is perf-neutral by construction).
//   scale0: x1 [4,512,16,16]  d=64 C=512 hs=16 Ns=256  R=161
//   scale1: x2 [4,256,32,32]  d=32 C=256 hs=32 Ns=1024 R=97
//   scale2: x3 [4,128,64,64]  d=16 C=128 hs=64 Ns=4096 R=65
// attn: double-buffered global_load_lds DMA staging (R25: VGPR 52, occ 37%,
// 75.5us — at the structural floor for this decomposition). Ledger: the
// other four kernels sum to ~180us/iter but never appear in top-5 (each
// <75us individually); ideal-case arithmetic says they should cost ~25us.
// This round buys visibility. Compute bit-identical throughout.
// ---------------------------------------------------------------------------

#define BB 4
#define LOG2E 1.44269504088896340736f

typedef __attribute__((ext_vector_type(8))) short short8;
typedef __attribute__((ext_vector_type(4))) float f32x4;

static constexpr int OFF_UP0 = 0;                        // [4][512]
static constexpr int OFF_UP1 = OFF_UP0 + 4 * 512;
static constexpr int OFF_UP2 = OFF_UP1 + 4 * 256;
static constexpr int OFF_UB0 = OFF_UP2 + 4 * 128;
static constexpr int OFF_UB1 = OFF_UB0 + 4;
static constexpr int OFF_UB2 = OFF_UB1 + 4;
static constexpr int OFF_PROJ0 = OFF_UB2 + 4;
static constexpr int OFF_PROJ1 = OFF_PROJ0 + BB * 161 * 256;
static constexpr int OFF_PROJ2 = OFF_PROJ1 + BB * 97 * 1024;
static constexpr int OFF_SBIG0 = OFF_PROJ2 + BB * 65 * 4096;   // [b][4096]
static constexpr int OFF_SBIG1 = OFF_SBIG0 + BB * 4096;        // [b][4096]
static constexpr int OFF_QP0 = OFF_SBIG1 + BB * 4096;          // BB*4096*64 fl
static constexpr int OFF_KF0 = OFF_QP0 + BB * 4096 * 64;       // BB*262144 fl
static constexpr int OFF_QP1 = OFF_KF0 + BB * 262144;          // BB*4096*32 fl
static constexpr int OFF_KF1 = OFF_QP1 + BB * 4096 * 32;       // BB*131072 fl
static constexpr int OFF_QP2 = OFF_KF1 + BB * 131072;          // BB*4096*16 fl
static constexpr int OFF_KF2 = OFF_QP2 + BB * 4096 * 16;       // BB*131072 fl
static constexpr int PS = BB * 4 * 4096;
static constexpr int OFF_PSN0 = OFF_KF2 + BB * 131072;
static constexpr int OFF_PSW0 = OFF_PSN0 + PS;
static constexpr int OFF_PSN1 = OFF_PSW0 + PS;
static constexpr int OFF_PSW1 = OFF_PSN1 + PS;
static constexpr int OFF_PSN2 = OFF_PSW1 + PS;
static constexpr int OFF_PSW2 = OFF_PSN2 + PS;

// ---- direct global->LDS DMA helpers (size literal; dest = base+lane*sz) ---
__device__ inline void gload_lds16(const void* g, void* l) {
    __builtin_amdgcn_global_load_lds((const __attribute__((address_space(1))) void*)g,
                                     (__attribute__((address_space(3))) void*)l, 16, 0, 0);
}
__device__ inline void gload_lds4(const void* g, void* l) {
    __builtin_amdgcn_global_load_lds((const __attribute__((address_space(1))) void*)g,
                                     (__attribute__((address_space(3))) void*)l, 4, 0, 0);
}

// --------------------------- u partials ------------------------------------
struct UArgs {
    const float *wv0, *wa0, *bv0;
    const float *wv1, *wa1, *bv1;
    const float *wv2, *wa2, *bv2;
    float* ws;
};

__global__ void u_kernel(UArgs A) {
    __shared__ float red[256];
    int idx = blockIdx.x, tid = threadIdx.x;
    int C, cit, chunk;
    const float *wv, *wa, *bv;
    float *up, *ub;
    if (idx < 32) {
        C = 512; cit = idx >> 2; chunk = idx & 3;
        wv = A.wv0; wa = A.wa0; bv = A.bv0;
        up = A.ws + OFF_UP0; ub = A.ws + OFF_UB0;
    } else if (idx < 48) {
        int i2 = idx - 32;
        C = 256; cit = i2 >> 2; chunk = i2 & 3;
        wv = A.wv1; wa = A.wa1; bv = A.bv1;
        up = A.ws + OFF_UP1; ub = A.ws + OFF_UB1;
    } else {
        int i2 = idx - 48;
        C = 128; cit = i2 >> 2; chunk = i2 & 3;
        wv = A.wv2; wa = A.wa2; bv = A.bv2;
        up = A.ws + OFF_UP2; ub = A.ws + OFF_UB2;
    }
    int lci = tid & 63, sub = tid >> 6;
    int ci = cit * 64 + lci;
    int coBeg = chunk * (C >> 2), coEnd = coBeg + (C >> 2);
    float acc = 0.f;
#pragma unroll 4
    for (int co = coBeg + sub; co < coEnd; co += 4)
        acc += wa[co] * wv[(size_t)co * C + ci];
    red[tid] = acc;
    __syncthreads();
    if (sub == 0)
        up[chunk * C + ci] = red[lci] + red[lci + 64] + red[lci + 128] + red[lci + 192];
    if (cit == 0) {
        __syncthreads();
        float bacc = 0.f;
        for (int co = coBeg + tid; co < coEnd; co += 256) bacc += wa[co] * bv[co];
        red[tid] = bacc;
        __syncthreads();
        for (int off = 128; off > 0; off >>= 1) {
            if (tid < off) red[tid] += red[tid + off];
            __syncthreads();
        }
        if (tid == 0) ub[chunk] = red[0];
    }
}

// --------------------------- proj: all scales, 16 rows/block, 2 m/thread ---
struct ProjArgs {
    const float *x0, *x1, *x2;
    const float *wq0, *wk0, *bq0, *bk0;
    const float *wq1, *wk1, *bq1, *bk1;
    const float *wq2, *wk2, *bq2, *bk2;
    const float *w1;
    float* ws;
};

__global__ __launch_bounds__(256) void proj_kernel(ProjArgs A) {
    __shared__ __align__(16) float Wl[512 * 16];  // [c][rr]
    __shared__ float bl[16];
    __shared__ float red[2048];
    int idx = blockIdx.x, tid = threadIdx.x;
    const float *x, *wq, *wk, *bq, *bk, *up, *ub;
    float* out;
    int C, Ns, R, nx, d, w1off, local;
    if (idx < 88) {
        local = idx; x = A.x0; out = A.ws + OFF_PROJ0;
        wq = A.wq0; wk = A.wk0; bq = A.bq0; bk = A.bk0;
        up = A.ws + OFF_UP0; ub = A.ws + OFF_UB0;
        C = 512; Ns = 256; R = 161; nx = 2; d = 64; w1off = 384;
    } else if (idx < 312) {
        local = idx - 88; x = A.x1; out = A.ws + OFF_PROJ1;
        wq = A.wq1; wk = A.wk1; bq = A.bq1; bk = A.bk1;
        up = A.ws + OFF_UP1; ub = A.ws + OFF_UB1;
        C = 256; Ns = 1024; R = 97; nx = 8; d = 32; w1off = 128;
    } else {
        local = idx - 312; x = A.x2; out = A.ws + OFF_PROJ2;
        wq = A.wq2; wk = A.wk2; bq = A.bq2; bk = A.bk2;
        up = A.ws + OFF_UP2; ub = A.ws + OFF_UB2;
        C = 128; Ns = 4096; R = 65; nx = 32; d = 16; w1off = 0;
    }
    int ny = (R + 15) >> 4;
    int pb = nx * ny;
    int b = local / pb;
    int rem = local - b * pb;
    int by = rem / nx;
    int bx = rem - by * nx;
    int r0 = by * 16;
    int nr = min(16, R - r0);
    for (int rp = 0; rp < 16; rp += 8) {
        int rr = rp + (tid >> 5), cg = tid & 31;
        int gr = r0 + rr;
        if (gr == 2 * d) {
            for (int c = cg; c < C; c += 32)
                Wl[c * 16 + rr] = up[c] + up[C + c] + up[2 * C + c] + up[3 * C + c];
        } else {
            const float* rowsrc;
            if (gr < d) rowsrc = wq + (size_t)gr * C;
            else if (gr < 2 * d) rowsrc = wk + (size_t)(gr - d) * C;
            else if (gr < R) rowsrc = A.w1 + (size_t)(gr - 2 * d - 1) * 896 + w1off;
            else rowsrc = nullptr;
            if (rowsrc) {
                for (int c = cg; c < C; c += 32) Wl[c * 16 + rr] = rowsrc[c];
            } else {
                for (int c = cg; c < C; c += 32) Wl[c * 16 + rr] = 0.f;
            }
        }
    }
    if (tid < 16) {
        int g2 = r0 + tid;
        float bv2;
        if (g2 < d) bv2 = bq[g2];
        else if (g2 < 2 * d) bv2 = bk[g2 - d];
        else if (g2 == 2 * d) bv2 = ub[0] + ub[1] + ub[2] + ub[3];
        else bv2 = 0.f;
        bl[tid] = bv2;
    }
    __syncthreads();
    int lane = tid & 63, strip = tid >> 6;
    int m0 = bx * 128 + lane * 2;
    const float* xb = x + (size_t)(b * C) * Ns + m0;
    float acc[16][2];
#pragma unroll
    for (int r = 0; r < 16; ++r) {
        acc[r][0] = 0.f;
        acc[r][1] = 0.f;
    }
    float2 buf[4];
#pragma unroll
    for (int j = 0; j < 4; ++j)
        buf[j] = *(const float2*)&xb[(size_t)(strip + 4 * j) * Ns];
    for (int c0 = strip; c0 < C; c0 += 16) {
#pragma unroll
        for (int j = 0; j < 4; ++j) {
            int c = c0 + 4 * j;
            float2 xv = buf[j];
            int cn = c + 16;
            if (cn < C) buf[j] = *(const float2*)&xb[(size_t)cn * Ns];
            const float* wl = &Wl[c * 16];
#pragma unroll
            for (int r4 = 0; r4 < 4; ++r4) {
                float4 w = *(const float4*)&wl[r4 * 4];
                acc[r4 * 4 + 0][0] += w.x * xv.x; acc[r4 * 4 + 0][1] += w.x * xv.y;
                acc[r4 * 4 + 1][0] += w.y * xv.x; acc[r4 * 4 + 1][1] += w.y * xv.y;
                acc[r4 * 4 + 2][0] += w.z * xv.x; acc[r4 * 4 + 2][1] += w.z * xv.y;
                acc[r4 * 4 + 3][0] += w.w * xv.x; acc[r4 * 4 + 3][1] += w.w * xv.y;
            }
        }
    }
    for (int rp = 0; rp < 16; rp += 4) {
        __syncthreads();
#pragma unroll
        for (int r = 0; r < 4; ++r)
#pragma unroll
            for (int j = 0; j < 2; ++j)
                red[((r * 2 + j) * 4 + strip) * 64 + lane] = acc[rp + r][j];
        __syncthreads();
        int g = tid >> 6;
        int rr2 = rp + g;
        if (rr2 < nr) {
            float v[2];
#pragma unroll
            for (int j = 0; j < 2; ++j) {
                int base = (g * 2 + j) * 256 + lane;
                v[j] = red[base] + red[base + 64] + red[base + 128] + red[base + 192] + bl[rr2];
            }
            float2 v2; v2.x = v[0]; v2.y = v[1];
            *(float2*)&out[(size_t)(b * R + r0 + rr2) * Ns + m0] = v2;
        }
    }
}

// --------------------------- hi/lo split helper ----------------------------
__device__ inline void split_bf16(float f, ushort& hi, ushort& lo) {
    unsigned u = __float_as_uint(f);
    unsigned h = u >> 16;
    float r = f - __uint_as_float(h << 16);
    hi = (ushort)h;
    lo = (ushort)(__float_as_uint(r) >> 16);
}

// --------------------------- bilerp field values ---------------------------
template <int D, int HS>
__device__ void bilerp_vals(const float* __restrict__ proj, int R, int rowbase,
                            float scale, int b, int n, float* vals) {
    constexpr int NS = HS * HS;
    constexpr float f = (float)(HS - 1) / 63.0f;
    int oy = n >> 6, ox = n & 63;
    float cy = oy * f, cx = ox * f;
    int iy0 = min((int)cy, HS - 2);
    int ix0 = min((int)cx, HS - 2);
    float wy = cy - iy0, wx = cx - ix0;
    float w00 = (1.f - wy) * (1.f - wx) * scale, w01 = (1.f - wy) * wx * scale;
    float w10 = wy * (1.f - wx) * scale, w11 = wy * wx * scale;
    const float* pb = proj + ((size_t)b * R + rowbase) * NS + iy0 * HS + ix0;
#pragma unroll
    for (int d = 0; d < D; ++d) {
        const float* p = pb + (size_t)d * NS;
        vals[d] = w00 * p[0] + w01 * p[1] + w10 * p[HS] + w11 * p[HS + 1];
    }
}

// --------------------------- q pack ([n][2D] layout) -----------------------
template <int D>
__device__ void q_store(ushort* __restrict__ dst, const float* vals, int b, int n) {
    ushort outv[2 * D];
#pragma unroll
    for (int d = 0; d < D; ++d) split_bf16(vals[d], outv[d], outv[D + d]);
    ushort* dp = dst + (size_t)(b * 4096 + n) * (2 * D);
#pragma unroll
    for (int i = 0; i < D / 4; ++i)
        ((uint4*)dp)[i] = ((const uint4*)outv)[i];
}

// q pack for scale0, one 32-field chunk (chunk 0: d 0..31, chunk 1: 32..63).
__device__ void q_store_c32(ushort* __restrict__ dst, const float* vals,
                            int b, int n, int chunk) {
    ushort outv[64];
#pragma unroll
    for (int d = 0; d < 32; ++d) split_bf16(vals[d], outv[d], outv[32 + d]);
    ushort* dp = dst + (size_t)(b * 4096 + n) * 128;
#pragma unroll
    for (int i = 0; i < 4; ++i)
        ((uint4*)dp)[chunk * 4 + i] = ((const uint4*)outv)[i];
#pragma unroll
    for (int i = 0; i < 4; ++i)
        ((uint4*)dp)[8 + chunk * 4 + i] = ((const uint4*)outv)[4 + i];
}

// --------------------------- k pack (fragment order) -----------------------
template <int D>
__device__ void k_store(ushort* __restrict__ dst, const float* vals, int b, int n) {
    constexpr int NC = (D == 16) ? 2 : (D / 32) * 2;
    ushort hi[D], lo[D];
#pragma unroll
    for (int d = 0; d < D; ++d) split_bf16(vals[d], hi[d], lo[d]);
    int tile = n >> 4, cc = n & 15;
    ushort* kb = dst + (size_t)b * (256 * NC * 512) + (size_t)tile * (NC * 512);
    if constexpr (D == 16) {
#pragma unroll
        for (int combo = 0; combo < 2; ++combo)
#pragma unroll
            for (int quad = 0; quad < 4; ++quad) {
                const ushort* src = (combo == 0 ? hi : lo) + (quad & 1) * 8;
                ushort* dp = kb + ((size_t)combo * 512 + (quad * 16 + cc) * 8);
                *(uint4*)dp = *(const uint4*)src;
            }
    } else {
#pragma unroll
        for (int h = 0; h < D / 32; ++h)
#pragma unroll
            for (int part = 0; part < 2; ++part) {
                int combo = h * 2 + part;
#pragma unroll
                for (int quad = 0; quad < 4; ++quad) {
                    const ushort* src = (part == 0 ? hi : lo) + h * 32 + quad * 8;
                    ushort* dp = kb + ((size_t)combo * 512 + (quad * 16 + cc) * 8);
                    *(uint4*)dp = *(const uint4*)src;
                }
            }
    }
}

// k pack for scale0, one 32-field chunk (h = chunk): writes combos
// {chunk*2, chunk*2+1} — disjoint across chunks, bit-identical union.
__device__ void k_store_c32(ushort* __restrict__ dst, const float* vals,
                            int b, int n, int chunk) {
    ushort hi[32], lo[32];
#pragma unroll
    for (int d = 0; d < 32; ++d) split_bf16(vals[d], hi[d], lo[d]);
    int tile = n >> 4, cc = n & 15;
    ushort* kb = dst + (size_t)b * (256 * 4 * 512) + (size_t)tile * (4 * 512);
#pragma unroll
    for (int part = 0; part < 2; ++part) {
        int combo = chunk * 2 + part;
#pragma unroll
        for (int quad = 0; quad < 4; ++quad) {
            const ushort* src = (part == 0 ? hi : lo) + quad * 8;
            ushort* dp = kb + ((size_t)combo * 512 + (quad * 16 + cc) * 8);
            *(uint4*)dp = *(const uint4*)src;
        }
    }
}

// --------------------------- native field values (scale2) ------------------
__device__ void nat_vals(const float* __restrict__ proj, int rowbase, float scale,
                         int b, int n, float* vals) {
    const float* pb = proj + ((size_t)b * 65 + rowbase) * 4096 + n;
#pragma unroll
    for (int d = 0; d < 16; ++d) vals[d] = pb[(size_t)d * 4096] * scale;
}

// --------------------------- mid: upsample-s + packs -----------------------
__global__ __launch_bounds__(256) void mid_kernel(float* ws) {
    int idx = blockIdx.x, tid = threadIdx.x;
    if (idx < 128) {
        int gi = idx * 256 + tid;
        int seg = gi >> 14;
        int li = gi & 16383;
        int b = li >> 12, n = li & 4095;
        const float* src;
        float* dst;
        int hs;
        if (seg == 0) { src = ws + OFF_PROJ0 + (b * 161 + 128) * 256;  dst = ws + OFF_SBIG0; hs = 16; }
        else          { src = ws + OFF_PROJ1 + (b * 97 + 64) * 1024;   dst = ws + OFF_SBIG1; hs = 32; }
        int oy = n >> 6, ox = n & 63;
        float f = (float)(hs - 1) / 63.0f;
        float cy = oy * f, cx = ox * f;
        int iy0 = min((int)cy, hs - 2);
        int ix0 = min((int)cx, hs - 2);
        float wy = cy - iy0, wx = cx - ix0;
        float v00 = src[iy0 * hs + ix0], v01 = src[iy0 * hs + ix0 + 1];
        float v10 = src[(iy0 + 1) * hs + ix0], v11 = src[(iy0 + 1) * hs + ix0 + 1];
        float t0 = v00 + wx * (v01 - v00), t1 = v10 + wx * (v11 - v10);
        dst[b * 4096 + n] = t0 + wy * (t1 - t0);
    } else if (idx < 384) {
        int li = idx - 128;               // 0..255: scale0, 2 chunks
        int field = li >> 7;
        int rest = li & 127;
        int b = rest >> 5;
        int nt = (rest >> 1) & 15;
        int chunk = rest & 1;
        int n = nt * 256 + tid;
        float vals[32];
        if (field == 0) {
            bilerp_vals<32, 16>(ws + OFF_PROJ0, 161, chunk * 32, LOG2E, b, n, vals);
            q_store_c32((ushort*)(ws + OFF_QP0), vals, b, n, chunk);
        } else {
            bilerp_vals<32, 16>(ws + OFF_PROJ0, 161, 64 + chunk * 32, 1.0f, b, n, vals);
            k_store_c32((ushort*)(ws + OFF_KF0), vals, b, n, chunk);
        }
    } else if (idx < 512) {
        int li = idx - 384;
        int field = li >> 6, b = (li >> 4) & 3, nt = li & 15;
        int n = nt * 256 + tid;
        float vals[32];
        if (field == 0) {
            bilerp_vals<32, 32>(ws + OFF_PROJ1, 97, 0, LOG2E, b, n, vals);
            q_store<32>((ushort*)(ws + OFF_QP1), vals, b, n);
        } else {
            bilerp_vals<32, 32>(ws + OFF_PROJ1, 97, 32, 1.0f, b, n, vals);
            k_store<32>((ushort*)(ws + OFF_KF1), vals, b, n);
        }
    } else {
        int li = idx - 512;
        int field = li >> 6, b = (li >> 4) & 3, nt = li & 15;
        int n = nt * 256 + tid;
        float vals[16];
        if (field == 0) {
            nat_vals(ws + OFF_PROJ2, 0, LOG2E, b, n, vals);
            q_store<16>((ushort*)(ws + OFF_QP2), vals, b, n);
        } else {
            nat_vals(ws + OFF_PROJ2, 16, 1.0f, b, n, vals);
            k_store<16>((ushort*)(ws + OFF_KF2), vals, b, n);
        }
    }
}

// --------------------------- MFMA attention body ---------------------------
// Double-buffered DMA staging (R25): global_load_lds issues stage s+1's
// k/s loads right after the stage-s barrier; they land in LDS buf[cur^1]
// during stage-s compute. ONE barrier per stage. Stage loop NOT unrolled
// (R24: full unroll -> 216 VGPR). Bit-exact vs R16.
template <int D>
__device__ void attn_mfma_body(const ushort* __restrict__ qp, const ushort* __restrict__ kf,
                               const float* __restrict__ srow,
                               float* __restrict__ pSn, float* __restrict__ pSw,
                               int nblk, int mc, int b, int tid,
                               ushort (*kst)[8192], float (*sst)[128]) {
    constexpr int NC = (D == 16) ? 2 : (D / 32) * 2;
    constexpr int ST = 16 / NC;       // tiles per stage (stage = 16 KB)
    constexpr int NF = (D >= 32) ? (D / 32) : 1;
    constexpr int NSTG = 64 / ST;     // stages per 1024-m chunk
    int wave = tid >> 6, lane = tid & 63;
    int cc = lane & 15, quad = lane >> 4;
    int n0 = (nblk * 4 + wave) * 16;
    const ushort* qn = qp + (size_t)(b * 4096 + n0 + cc) * (2 * D);
    short8 Ah[NF], Al[NF];
    if constexpr (D == 16) {
        Ah[0] = *(const short8*)(qn + quad * 8);   // [qh16|ql16] spans k=0..31
    } else {
#pragma unroll
        for (int h = 0; h < NF; ++h) {
            Ah[h] = *(const short8*)(qn + h * 32 + quad * 8);
            Al[h] = *(const short8*)(qn + D + h * 32 + quad * 8);
        }
    }
    float Sn[4] = {0.f, 0.f, 0.f, 0.f};
    float Sw[4] = {0.f, 0.f, 0.f, 0.f};
    int tbase = mc * 64;
    const uint4* gk = (const uint4*)(kf + (size_t)b * (256 * NC * 512) +
                                     (size_t)tbase * (NC * 512));
    const float* gs = srow + tbase * 16;

    // prologue: DMA stage 0 into buffer 0
#pragma unroll
    for (int i = 0; i < 4; ++i)
        gload_lds16(gk + tid + i * 256, (uint4*)kst[0] + tid + i * 256);
    if (tid < ST * 16) gload_lds4(gs + tid, &sst[0][tid]);

#pragma unroll 1
    for (int st = 0; st < NSTG; ++st) {
        int cur = st & 1;
        __syncthreads();   // drains DMA for buf[cur]
        if (st + 1 < NSTG) {
#pragma unroll
            for (int i = 0; i < 4; ++i)
                gload_lds16(gk + (size_t)(st + 1) * 1024 + tid + i * 256,
                            (uint4*)kst[cur ^ 1] + tid + i * 256);
            if (tid < ST * 16)
                gload_lds4(gs + (st + 1) * ST * 16 + tid, &sst[cur ^ 1][tid]);
        }
        const ushort* kl = kst[cur] + lane * 8;
#pragma unroll
        for (int t = 0; t < ST; ++t) {
            short8 Bf[NC];
#pragma unroll
            for (int cb = 0; cb < NC; ++cb)
                Bf[cb] = *(const short8*)(kl + (t * NC + cb) * 512);
            float sv = sst[cur][t * 16 + cc];
            f32x4 c = {0.f, 0.f, 0.f, 0.f};
            if constexpr (D == 16) {
                c = __builtin_amdgcn_mfma_f32_16x16x32_bf16(Ah[0], Bf[1], c, 0, 0, 0);
                c = __builtin_amdgcn_mfma_f32_16x16x32_bf16(Ah[0], Bf[0], c, 0, 0, 0);
            } else {
#pragma unroll
                for (int h = 0; h < NF; ++h) {
                    c = __builtin_amdgcn_mfma_f32_16x16x32_bf16(Ah[h], Bf[h * 2 + 1], c, 0, 0, 0);
                    c = __builtin_amdgcn_mfma_f32_16x16x32_bf16(Al[h], Bf[h * 2], c, 0, 0, 0);
                    c = __builtin_amdgcn_mfma_f32_16x16x32_bf16(Al[h], Bf[h * 2 + 1], c, 0, 0, 0);
                    c = __builtin_amdgcn_mfma_f32_16x16x32_bf16(Ah[h], Bf[h * 2], c, 0, 0, 0);
                }
            }
#pragma unroll
            for (int r = 0; r < 4; ++r) {
                float e = __builtin_amdgcn_exp2f(c[r]);
                Sn[r] += e;
                Sw[r] += e * sv;
            }
        }
    }
#pragma unroll
    for (int mask = 1; mask < 16; mask <<= 1) {
#pragma unroll
        for (int r = 0; r < 4; ++r) {
            Sn[r] += __shfl_xor(Sn[r], mask, 64);
            Sw[r] += __shfl_xor(Sw[r], mask, 64);
        }
    }
    if (cc == 0) {
        int n = n0 + quad * 4;
        int pidx = (b * 4 + mc) * 4096 + n;
        *(float4*)&pSn[pidx] = make_float4(Sn[0], Sn[1], Sn[2], Sn[3]);
        *(float4*)&pSw[pidx] = make_float4(Sw[0], Sw[1], Sw[2], Sw[3]);
    }
}

// --------------------------- attn: one kernel per scale --------------------
// 1024 blocks each (64 nblk * 4 mc * 4 b); LDS 33.8 KB -> 4 blocks/CU,
// all blocks resident. Split is perf-neutral vs merged (same resident
// rounds) but surfaces the other kernels' durations in rocprof top-5.
__global__ __launch_bounds__(256) void attn0_kernel(float* ws) {
    __shared__ __align__(16) ushort kst[2][8192];
    __shared__ float sst[2][128];
    int idx = blockIdx.x, tid = threadIdx.x;
    int nblk = idx & 63, mc = (idx >> 6) & 3, b = idx >> 8;
    attn_mfma_body<64>((const ushort*)(ws + OFF_QP0), (const ushort*)(ws + OFF_KF0),
                       ws + OFF_SBIG0 + b * 4096,
                       ws + OFF_PSN0, ws + OFF_PSW0, nblk, mc, b, tid, kst, sst);
}

__global__ __launch_bounds__(256) void attn1_kernel(float* ws) {
    __shared__ __align__(16) ushort kst[2][8192];
    __shared__ float sst[2][128];
    int idx = blockIdx.x, tid = threadIdx.x;
    int nblk = idx & 63, mc = (idx >> 6) & 3, b = idx >> 8;
    attn_mfma_body<32>((const ushort*)(ws + OFF_QP1), (const ushort*)(ws + OFF_KF1),
                       ws + OFF_SBIG1 + b * 4096,
                       ws + OFF_PSN1, ws + OFF_PSW1, nblk, mc, b, tid, kst, sst);
}

__global__ __launch_bounds__(256) void attn2_kernel(float* ws) {
    __shared__ __align__(16) ushort kst[2][8192];
    __shared__ float sst[2][128];
    int idx = blockIdx.x, tid = threadIdx.x;
    int nblk = idx & 63, mc = (idx >> 6) & 3, b = idx >> 8;
    attn_mfma_body<16>((const ushort*)(ws + OFF_QP2), (const ushort*)(ws + OFF_KF2),
                       ws + OFF_PROJ2 + ((size_t)b * 65 + 32) * 4096,
                       ws + OFF_PSN2, ws + OFF_PSW2, nblk, mc, b, tid, kst, sst);
}

// --------------------------- final: combine + fusion -----------------------
__global__ __launch_bounds__(256) void final_kernel(const float* __restrict__ ws,
                                                    const float* __restrict__ ba0,
                                                    const float* __restrict__ ba1,
                                                    const float* __restrict__ ba2,
                                                    const float* __restrict__ b1,
                                                    const float* __restrict__ w2,
                                                    const float* __restrict__ b2,
                                                    float* __restrict__ out) {
    __shared__ float lb1[32], lw2[32];
    int tid = threadIdx.x;
    if (tid < 32) { lb1[tid] = b1[tid]; lw2[tid] = w2[tid]; }
    __syncthreads();
    int b = blockIdx.y;
    int n = blockIdx.x * 256 + tid;
    const float* pSns[3] = {ws + OFF_PSN0, ws + OFF_PSN1, ws + OFF_PSN2};
    const float* pSws[3] = {ws + OFF_PSW0, ws + OFF_PSW1, ws + OFF_PSW2};
    float aval[3];
#pragma unroll
    for (int s = 0; s < 3; ++s) {
        float Sn = 0.f, Sw = 0.f;
#pragma unroll
        for (int ch = 0; ch < 4; ++ch) {
            int pi = (b * 4 + ch) * 4096 + n;
            Sn += pSns[s][pi];
            Sw += pSws[s][pi];
        }
        float bav = (s == 0) ? ba0[0] : (s == 1) ? ba1[0] : ba2[0];
        aval[s] = Sw / Sn + bav;
    }
    float prod = aval[0] * aval[1] * aval[2];
    int oy = n >> 6, ox = n & 63;
    float f0 = 15.0f / 63.0f;
    float cy0 = oy * f0, cx0 = ox * f0;
    int iy0 = min((int)cy0, 14), ix0 = min((int)cx0, 14);
    float wy0 = cy0 - iy0, wx0 = cx0 - ix0;
    float f1 = 31.0f / 63.0f;
    float cy1 = oy * f1, cx1 = ox * f1;
    int iy1 = min((int)cy1, 30), ix1 = min((int)cx1, 30);
    float wy1 = cy1 - iy1, wx1 = cx1 - ix1;
    const float* g0b = ws + OFF_PROJ0 + (b * 161 + 129) * 256;
    const float* g1b = ws + OFF_PROJ1 + (b * 97 + 65) * 1024;
    const float* g2b = ws + OFF_PROJ2 + (b * 65 + 33) * 4096;
    float outv = 0.f;
#pragma unroll 4
    for (int j = 0; j < 32; ++j) {
        const float* p0 = g0b + j * 256;
        float v0 = (1.f - wy0) * ((1.f - wx0) * p0[iy0 * 16 + ix0] + wx0 * p0[iy0 * 16 + ix0 + 1]) +
                   wy0 * ((1.f - wx0) * p0[(iy0 + 1) * 16 + ix0] + wx0 * p0[(iy0 + 1) * 16 + ix0 + 1]);
        const float* p1 = g1b + j * 1024;
        float v1 = (1.f - wy1) * ((1.f - wx1) * p1[iy1 * 32 + ix1] + wx1 * p1[iy1 * 32 + ix1 + 1]) +
                   wy1 * ((1.f - wx1) * p1[(iy1 + 1) * 32 + ix1] + wx1 * p1[(iy1 + 1) * 32 + ix1 + 1]);
        float g = g2b[j * 4096 + n] + v0 + v1;
        float h = fmaxf(prod * g + lb1[j], 0.f);
        outv += lw2[j] * h;
    }
    out[b * 4096 + n] = outv + b2[0];
}

// ---------------------------------------------------------------------------
extern "C" void kernel_launch(void* const* d_in, const int* in_sizes, int n_in,
                              void* d_out, int out_size, void* d_ws, size_t ws_size,
                              hipStream_t stream) {
    const float* x3 = (const float*)d_in[0];
    const float* x2 = (const float*)d_in[1];
    const float* x1 = (const float*)d_in[2];
    const float* W[24];
    for (int i = 0; i < 24; ++i) W[i] = (const float*)d_in[3 + i];
    const float* w1 = (const float*)d_in[27];
    const float* b1 = (const float*)d_in[28];
    const float* w2 = (const float*)d_in[29];
    const float* b2 = (const float*)d_in[30];
    float* ws = (float*)d_ws;
    float* out = (float*)d_out;

    UArgs ua;
    ua.wv0 = W[4];  ua.wa0 = W[6];  ua.bv0 = W[5];
    ua.wv1 = W[12]; ua.wa1 = W[14]; ua.bv1 = W[13];
    ua.wv2 = W[20]; ua.wa2 = W[22]; ua.bv2 = W[21];
    ua.ws = ws;
    u_kernel<<<56, 256, 0, stream>>>(ua);

    ProjArgs ja;
    ja.x0 = x1; ja.x1 = x2; ja.x2 = x3;
    ja.wq0 = W[0];  ja.wk0 = W[2];  ja.bq0 = W[1];  ja.bk0 = W[3];
    ja.wq1 = W[8];  ja.wk1 = W[10]; ja.bq1 = W[9];  ja.bk1 = W[11];
    ja.wq2 = W[16]; ja.wk2 = W[18]; ja.bq2 = W[17]; ja.bk2 = W[19];
    ja.w1 = w1; ja.ws = ws;
    proj_kernel<<<952, 256, 0, stream>>>(ja);

    mid_kernel<<<640, 256, 0, stream>>>(ws);

    attn0_kernel<<<1024, 256, 0, stream>>>(ws);
    attn1_kernel<<<1024, 256, 0, stream>>>(ws);
    attn2_kernel<<<1024, 256, 0, stream>>>(ws);

    final_kernel<<<dim3(16, BB), 256, 0, stream>>>(ws, W[7], W[15], W[23],
                                                   b1, w2, b2, out);
}

// Round 12
// 253.957 us; speedup vs baseline: 1.2122x; 1.0174x over previous
//
#include <hip/hip_runtime.h>

// ---------------------------------------------------------------------------
// MultiScaleFeatureFusion — R27 (= R25 + final_kernel re-gridded).
//   scale0: x1 [4,512,16,16]  d=64 C=512 hs=16 Ns=256  R=161
//   scale1: x2 [4,256,32,32]  d=32 C=256 hs=32 Ns=1024 R=97
//   scale2: x3 [4,128,64,64]  d=16 C=128 hs=64 Ns=4096 R=65
// LEDGER (R26 diagnostic): harness poison-fill of the 256 MiB workspace
// (42us @6.4TB/s) + ~32 input-restore dispatches run INSIDE the timed
// stream every iteration (~88us fixed tax). All our kernels are <42us.
// attn (merged, R25 DMA double-buffer) = 75.5us, at its structural floor.
// final_kernel ran 1 thread/output on a 64-block grid -> only 64/256 CUs
// busy, latency-bound (~288 loads/thread). R27: identical per-thread work,
// 64-thread blocks -> 256 blocks -> 4x CU coverage (bit-exact).
// ---------------------------------------------------------------------------

#define BB 4
#define LOG2E 1.44269504088896340736f

typedef __attribute__((ext_vector_type(8))) short short8;
typedef __attribute__((ext_vector_type(4))) float f32x4;

static constexpr int OFF_UP0 = 0;                        // [4][512]
static constexpr int OFF_UP1 = OFF_UP0 + 4 * 512;
static constexpr int OFF_UP2 = OFF_UP1 + 4 * 256;
static constexpr int OFF_UB0 = OFF_UP2 + 4 * 128;
static constexpr int OFF_UB1 = OFF_UB0 + 4;
static constexpr int OFF_UB2 = OFF_UB1 + 4;
static constexpr int OFF_PROJ0 = OFF_UB2 + 4;
static constexpr int OFF_PROJ1 = OFF_PROJ0 + BB * 161 * 256;
static constexpr int OFF_PROJ2 = OFF_PROJ1 + BB * 97 * 1024;
static constexpr int OFF_SBIG0 = OFF_PROJ2 + BB * 65 * 4096;   // [b][4096]
static constexpr int OFF_SBIG1 = OFF_SBIG0 + BB * 4096;        // [b][4096]
static constexpr int OFF_QP0 = OFF_SBIG1 + BB * 4096;          // BB*4096*64 fl
static constexpr int OFF_KF0 = OFF_QP0 + BB * 4096 * 64;       // BB*262144 fl
static constexpr int OFF_QP1 = OFF_KF0 + BB * 262144;          // BB*4096*32 fl
static constexpr int OFF_KF1 = OFF_QP1 + BB * 4096 * 32;       // BB*131072 fl
static constexpr int OFF_QP2 = OFF_KF1 + BB * 131072;          // BB*4096*16 fl
static constexpr int OFF_KF2 = OFF_QP2 + BB * 4096 * 16;       // BB*131072 fl
static constexpr int PS = BB * 4 * 4096;
static constexpr int OFF_PSN0 = OFF_KF2 + BB * 131072;
static constexpr int OFF_PSW0 = OFF_PSN0 + PS;
static constexpr int OFF_PSN1 = OFF_PSW0 + PS;
static constexpr int OFF_PSW1 = OFF_PSN1 + PS;
static constexpr int OFF_PSN2 = OFF_PSW1 + PS;
static constexpr int OFF_PSW2 = OFF_PSN2 + PS;

// ---- direct global->LDS DMA helpers (size literal; dest = base+lane*sz) ---
__device__ inline void gload_lds16(const void* g, void* l) {
    __builtin_amdgcn_global_load_lds((const __attribute__((address_space(1))) void*)g,
                                     (__attribute__((address_space(3))) void*)l, 16, 0, 0);
}
__device__ inline void gload_lds4(const void* g, void* l) {
    __builtin_amdgcn_global_load_lds((const __attribute__((address_space(1))) void*)g,
                                     (__attribute__((address_space(3))) void*)l, 4, 0, 0);
}

// --------------------------- u partials ------------------------------------
struct UArgs {
    const float *wv0, *wa0, *bv0;
    const float *wv1, *wa1, *bv1;
    const float *wv2, *wa2, *bv2;
    float* ws;
};

__global__ void u_kernel(UArgs A) {
    __shared__ float red[256];
    int idx = blockIdx.x, tid = threadIdx.x;
    int C, cit, chunk;
    const float *wv, *wa, *bv;
    float *up, *ub;
    if (idx < 32) {
        C = 512; cit = idx >> 2; chunk = idx & 3;
        wv = A.wv0; wa = A.wa0; bv = A.bv0;
        up = A.ws + OFF_UP0; ub = A.ws + OFF_UB0;
    } else if (idx < 48) {
        int i2 = idx - 32;
        C = 256; cit = i2 >> 2; chunk = i2 & 3;
        wv = A.wv1; wa = A.wa1; bv = A.bv1;
        up = A.ws + OFF_UP1; ub = A.ws + OFF_UB1;
    } else {
        int i2 = idx - 48;
        C = 128; cit = i2 >> 2; chunk = i2 & 3;
        wv = A.wv2; wa = A.wa2; bv = A.bv2;
        up = A.ws + OFF_UP2; ub = A.ws + OFF_UB2;
    }
    int lci = tid & 63, sub = tid >> 6;
    int ci = cit * 64 + lci;
    int coBeg = chunk * (C >> 2), coEnd = coBeg + (C >> 2);
    float acc = 0.f;
#pragma unroll 4
    for (int co = coBeg + sub; co < coEnd; co += 4)
        acc += wa[co] * wv[(size_t)co * C + ci];
    red[tid] = acc;
    __syncthreads();
    if (sub == 0)
        up[chunk * C + ci] = red[lci] + red[lci + 64] + red[lci + 128] + red[lci + 192];
    if (cit == 0) {
        __syncthreads();
        float bacc = 0.f;
        for (int co = coBeg + tid; co < coEnd; co += 256) bacc += wa[co] * bv[co];
        red[tid] = bacc;
        __syncthreads();
        for (int off = 128; off > 0; off >>= 1) {
            if (tid < off) red[tid] += red[tid + off];
            __syncthreads();
        }
        if (tid == 0) ub[chunk] = red[0];
    }
}

// --------------------------- proj: all scales, 16 rows/block, 2 m/thread ---
struct ProjArgs {
    const float *x0, *x1, *x2;
    const float *wq0, *wk0, *bq0, *bk0;
    const float *wq1, *wk1, *bq1, *bk1;
    const float *wq2, *wk2, *bq2, *bk2;
    const float *w1;
    float* ws;
};

__global__ __launch_bounds__(256) void proj_kernel(ProjArgs A) {
    __shared__ __align__(16) float Wl[512 * 16];  // [c][rr]
    __shared__ float bl[16];
    __shared__ float red[2048];
    int idx = blockIdx.x, tid = threadIdx.x;
    const float *x, *wq, *wk, *bq, *bk, *up, *ub;
    float* out;
    int C, Ns, R, nx, d, w1off, local;
    if (idx < 88) {
        local = idx; x = A.x0; out = A.ws + OFF_PROJ0;
        wq = A.wq0; wk = A.wk0; bq = A.bq0; bk = A.bk0;
        up = A.ws + OFF_UP0; ub = A.ws + OFF_UB0;
        C = 512; Ns = 256; R = 161; nx = 2; d = 64; w1off = 384;
    } else if (idx < 312) {
        local = idx - 88; x = A.x1; out = A.ws + OFF_PROJ1;
        wq = A.wq1; wk = A.wk1; bq = A.bq1; bk = A.bk1;
        up = A.ws + OFF_UP1; ub = A.ws + OFF_UB1;
        C = 256; Ns = 1024; R = 97; nx = 8; d = 32; w1off = 128;
    } else {
        local = idx - 312; x = A.x2; out = A.ws + OFF_PROJ2;
        wq = A.wq2; wk = A.wk2; bq = A.bq2; bk = A.bk2;
        up = A.ws + OFF_UP2; ub = A.ws + OFF_UB2;
        C = 128; Ns = 4096; R = 65; nx = 32; d = 16; w1off = 0;
    }
    int ny = (R + 15) >> 4;
    int pb = nx * ny;
    int b = local / pb;
    int rem = local - b * pb;
    int by = rem / nx;
    int bx = rem - by * nx;
    int r0 = by * 16;
    int nr = min(16, R - r0);
    for (int rp = 0; rp < 16; rp += 8) {
        int rr = rp + (tid >> 5), cg = tid & 31;
        int gr = r0 + rr;
        if (gr == 2 * d) {
            for (int c = cg; c < C; c += 32)
                Wl[c * 16 + rr] = up[c] + up[C + c] + up[2 * C + c] + up[3 * C + c];
        } else {
            const float* rowsrc;
            if (gr < d) rowsrc = wq + (size_t)gr * C;
            else if (gr < 2 * d) rowsrc = wk + (size_t)(gr - d) * C;
            else if (gr < R) rowsrc = A.w1 + (size_t)(gr - 2 * d - 1) * 896 + w1off;
            else rowsrc = nullptr;
            if (rowsrc) {
                for (int c = cg; c < C; c += 32) Wl[c * 16 + rr] = rowsrc[c];
            } else {
                for (int c = cg; c < C; c += 32) Wl[c * 16 + rr] = 0.f;
            }
        }
    }
    if (tid < 16) {
        int g2 = r0 + tid;
        float bv2;
        if (g2 < d) bv2 = bq[g2];
        else if (g2 < 2 * d) bv2 = bk[g2 - d];
        else if (g2 == 2 * d) bv2 = ub[0] + ub[1] + ub[2] + ub[3];
        else bv2 = 0.f;
        bl[tid] = bv2;
    }
    __syncthreads();
    int lane = tid & 63, strip = tid >> 6;
    int m0 = bx * 128 + lane * 2;
    const float* xb = x + (size_t)(b * C) * Ns + m0;
    float acc[16][2];
#pragma unroll
    for (int r = 0; r < 16; ++r) {
        acc[r][0] = 0.f;
        acc[r][1] = 0.f;
    }
    float2 buf[4];
#pragma unroll
    for (int j = 0; j < 4; ++j)
        buf[j] = *(const float2*)&xb[(size_t)(strip + 4 * j) * Ns];
    for (int c0 = strip; c0 < C; c0 += 16) {
#pragma unroll
        for (int j = 0; j < 4; ++j) {
            int c = c0 + 4 * j;
            float2 xv = buf[j];
            int cn = c + 16;
            if (cn < C) buf[j] = *(const float2*)&xb[(size_t)cn * Ns];
            const float* wl = &Wl[c * 16];
#pragma unroll
            for (int r4 = 0; r4 < 4; ++r4) {
                float4 w = *(const float4*)&wl[r4 * 4];
                acc[r4 * 4 + 0][0] += w.x * xv.x; acc[r4 * 4 + 0][1] += w.x * xv.y;
                acc[r4 * 4 + 1][0] += w.y * xv.x; acc[r4 * 4 + 1][1] += w.y * xv.y;
                acc[r4 * 4 + 2][0] += w.z * xv.x; acc[r4 * 4 + 2][1] += w.z * xv.y;
                acc[r4 * 4 + 3][0] += w.w * xv.x; acc[r4 * 4 + 3][1] += w.w * xv.y;
            }
        }
    }
    for (int rp = 0; rp < 16; rp += 4) {
        __syncthreads();
#pragma unroll
        for (int r = 0; r < 4; ++r)
#pragma unroll
            for (int j = 0; j < 2; ++j)
                red[((r * 2 + j) * 4 + strip) * 64 + lane] = acc[rp + r][j];
        __syncthreads();
        int g = tid >> 6;
        int rr2 = rp + g;
        if (rr2 < nr) {
            float v[2];
#pragma unroll
            for (int j = 0; j < 2; ++j) {
                int base = (g * 2 + j) * 256 + lane;
                v[j] = red[base] + red[base + 64] + red[base + 128] + red[base + 192] + bl[rr2];
            }
            float2 v2; v2.x = v[0]; v2.y = v[1];
            *(float2*)&out[(size_t)(b * R + r0 + rr2) * Ns + m0] = v2;
        }
    }
}

// --------------------------- hi/lo split helper ----------------------------
__device__ inline void split_bf16(float f, ushort& hi, ushort& lo) {
    unsigned u = __float_as_uint(f);
    unsigned h = u >> 16;
    float r = f - __uint_as_float(h << 16);
    hi = (ushort)h;
    lo = (ushort)(__float_as_uint(r) >> 16);
}

// --------------------------- bilerp field values ---------------------------
template <int D, int HS>
__device__ void bilerp_vals(const float* __restrict__ proj, int R, int rowbase,
                            float scale, int b, int n, float* vals) {
    constexpr int NS = HS * HS;
    constexpr float f = (float)(HS - 1) / 63.0f;
    int oy = n >> 6, ox = n & 63;
    float cy = oy * f, cx = ox * f;
    int iy0 = min((int)cy, HS - 2);
    int ix0 = min((int)cx, HS - 2);
    float wy = cy - iy0, wx = cx - ix0;
    float w00 = (1.f - wy) * (1.f - wx) * scale, w01 = (1.f - wy) * wx * scale;
    float w10 = wy * (1.f - wx) * scale, w11 = wy * wx * scale;
    const float* pb = proj + ((size_t)b * R + rowbase) * NS + iy0 * HS + ix0;
#pragma unroll
    for (int d = 0; d < D; ++d) {
        const float* p = pb + (size_t)d * NS;
        vals[d] = w00 * p[0] + w01 * p[1] + w10 * p[HS] + w11 * p[HS + 1];
    }
}

// --------------------------- q pack ([n][2D] layout) -----------------------
template <int D>
__device__ void q_store(ushort* __restrict__ dst, const float* vals, int b, int n) {
    ushort outv[2 * D];
#pragma unroll
    for (int d = 0; d < D; ++d) split_bf16(vals[d], outv[d], outv[D + d]);
    ushort* dp = dst + (size_t)(b * 4096 + n) * (2 * D);
#pragma unroll
    for (int i = 0; i < D / 4; ++i)
        ((uint4*)dp)[i] = ((const uint4*)outv)[i];
}

// q pack for scale0, one 32-field chunk (chunk 0: d 0..31, chunk 1: 32..63).
__device__ void q_store_c32(ushort* __restrict__ dst, const float* vals,
                            int b, int n, int chunk) {
    ushort outv[64];
#pragma unroll
    for (int d = 0; d < 32; ++d) split_bf16(vals[d], outv[d], outv[32 + d]);
    ushort* dp = dst + (size_t)(b * 4096 + n) * 128;
#pragma unroll
    for (int i = 0; i < 4; ++i)
        ((uint4*)dp)[chunk * 4 + i] = ((const uint4*)outv)[i];
#pragma unroll
    for (int i = 0; i < 4; ++i)
        ((uint4*)dp)[8 + chunk * 4 + i] = ((const uint4*)outv)[4 + i];
}

// --------------------------- k pack (fragment order) -----------------------
template <int D>
__device__ void k_store(ushort* __restrict__ dst, const float* vals, int b, int n) {
    constexpr int NC = (D == 16) ? 2 : (D / 32) * 2;
    ushort hi[D], lo[D];
#pragma unroll
    for (int d = 0; d < D; ++d) split_bf16(vals[d], hi[d], lo[d]);
    int tile = n >> 4, cc = n & 15;
    ushort* kb = dst + (size_t)b * (256 * NC * 512) + (size_t)tile * (NC * 512);
    if constexpr (D == 16) {
#pragma unroll
        for (int combo = 0; combo < 2; ++combo)
#pragma unroll
            for (int quad = 0; quad < 4; ++quad) {
                const ushort* src = (combo == 0 ? hi : lo) + (quad & 1) * 8;
                ushort* dp = kb + ((size_t)combo * 512 + (quad * 16 + cc) * 8);
                *(uint4*)dp = *(const uint4*)src;
            }
    } else {
#pragma unroll
        for (int h = 0; h < D / 32; ++h)
#pragma unroll
            for (int part = 0; part < 2; ++part) {
                int combo = h * 2 + part;
#pragma unroll
                for (int quad = 0; quad < 4; ++quad) {
                    const ushort* src = (part == 0 ? hi : lo) + h * 32 + quad * 8;
                    ushort* dp = kb + ((size_t)combo * 512 + (quad * 16 + cc) * 8);
                    *(uint4*)dp = *(const uint4*)src;
                }
            }
    }
}

// k pack for scale0, one 32-field chunk (h = chunk): writes combos
// {chunk*2, chunk*2+1} — disjoint across chunks, bit-identical union.
__device__ void k_store_c32(ushort* __restrict__ dst, const float* vals,
                            int b, int n, int chunk) {
    ushort hi[32], lo[32];
#pragma unroll
    for (int d = 0; d < 32; ++d) split_bf16(vals[d], hi[d], lo[d]);
    int tile = n >> 4, cc = n & 15;
    ushort* kb = dst + (size_t)b * (256 * 4 * 512) + (size_t)tile * (4 * 512);
#pragma unroll
    for (int part = 0; part < 2; ++part) {
        int combo = chunk * 2 + part;
#pragma unroll
        for (int quad = 0; quad < 4; ++quad) {
            const ushort* src = (part == 0 ? hi : lo) + quad * 8;
            ushort* dp = kb + ((size_t)combo * 512 + (quad * 16 + cc) * 8);
            *(uint4*)dp = *(const uint4*)src;
        }
    }
}

// --------------------------- native field values (scale2) ------------------
__device__ void nat_vals(const float* __restrict__ proj, int rowbase, float scale,
                         int b, int n, float* vals) {
    const float* pb = proj + ((size_t)b * 65 + rowbase) * 4096 + n;
#pragma unroll
    for (int d = 0; d < 16; ++d) vals[d] = pb[(size_t)d * 4096] * scale;
}

// --------------------------- mid: upsample-s + packs -----------------------
__global__ __launch_bounds__(256) void mid_kernel(float* ws) {
    int idx = blockIdx.x, tid = threadIdx.x;
    if (idx < 128) {
        int gi = idx * 256 + tid;
        int seg = gi >> 14;
        int li = gi & 16383;
        int b = li >> 12, n = li & 4095;
        const float* src;
        float* dst;
        int hs;
        if (seg == 0) { src = ws + OFF_PROJ0 + (b * 161 + 128) * 256;  dst = ws + OFF_SBIG0; hs = 16; }
        else          { src = ws + OFF_PROJ1 + (b * 97 + 64) * 1024;   dst = ws + OFF_SBIG1; hs = 32; }
        int oy = n >> 6, ox = n & 63;
        float f = (float)(hs - 1) / 63.0f;
        float cy = oy * f, cx = ox * f;
        int iy0 = min((int)cy, hs - 2);
        int ix0 = min((int)cx, hs - 2);
        float wy = cy - iy0, wx = cx - ix0;
        float v00 = src[iy0 * hs + ix0], v01 = src[iy0 * hs + ix0 + 1];
        float v10 = src[(iy0 + 1) * hs + ix0], v11 = src[(iy0 + 1) * hs + ix0 + 1];
        float t0 = v00 + wx * (v01 - v00), t1 = v10 + wx * (v11 - v10);
        dst[b * 4096 + n] = t0 + wy * (t1 - t0);
    } else if (idx < 384) {
        int li = idx - 128;               // 0..255: scale0, 2 chunks
        int field = li >> 7;
        int rest = li & 127;
        int b = rest >> 5;
        int nt = (rest >> 1) & 15;
        int chunk = rest & 1;
        int n = nt * 256 + tid;
        float vals[32];
        if (field == 0) {
            bilerp_vals<32, 16>(ws + OFF_PROJ0, 161, chunk * 32, LOG2E, b, n, vals);
            q_store_c32((ushort*)(ws + OFF_QP0), vals, b, n, chunk);
        } else {
            bilerp_vals<32, 16>(ws + OFF_PROJ0, 161, 64 + chunk * 32, 1.0f, b, n, vals);
            k_store_c32((ushort*)(ws + OFF_KF0), vals, b, n, chunk);
        }
    } else if (idx < 512) {
        int li = idx - 384;
        int field = li >> 6, b = (li >> 4) & 3, nt = li & 15;
        int n = nt * 256 + tid;
        float vals[32];
        if (field == 0) {
            bilerp_vals<32, 32>(ws + OFF_PROJ1, 97, 0, LOG2E, b, n, vals);
            q_store<32>((ushort*)(ws + OFF_QP1), vals, b, n);
        } else {
            bilerp_vals<32, 32>(ws + OFF_PROJ1, 97, 32, 1.0f, b, n, vals);
            k_store<32>((ushort*)(ws + OFF_KF1), vals, b, n);
        }
    } else {
        int li = idx - 512;
        int field = li >> 6, b = (li >> 4) & 3, nt = li & 15;
        int n = nt * 256 + tid;
        float vals[16];
        if (field == 0) {
            nat_vals(ws + OFF_PROJ2, 0, LOG2E, b, n, vals);
            q_store<16>((ushort*)(ws + OFF_QP2), vals, b, n);
        } else {
            nat_vals(ws + OFF_PROJ2, 16, 1.0f, b, n, vals);
            k_store<16>((ushort*)(ws + OFF_KF2), vals, b, n);
        }
    }
}

// --------------------------- MFMA attention body ---------------------------
// Double-buffered DMA staging (R25): global_load_lds issues stage s+1's
// k/s loads right after the stage-s barrier; they land in LDS buf[cur^1]
// during stage-s compute. ONE barrier per stage. Stage loop NOT unrolled
// (R24: full unroll -> 216 VGPR). Bit-exact vs R16.
template <int D>
__device__ void attn_mfma_body(const ushort* __restrict__ qp, const ushort* __restrict__ kf,
                               const float* __restrict__ srow,
                               float* __restrict__ pSn, float* __restrict__ pSw,
                               int nblk, int mc, int b, int tid,
                               ushort (*kst)[8192], float (*sst)[128]) {
    constexpr int NC = (D == 16) ? 2 : (D / 32) * 2;
    constexpr int ST = 16 / NC;       // tiles per stage (stage = 16 KB)
    constexpr int NF = (D >= 32) ? (D / 32) : 1;
    constexpr int NSTG = 64 / ST;     // stages per 1024-m chunk
    int wave = tid >> 6, lane = tid & 63;
    int cc = lane & 15, quad = lane >> 4;
    int n0 = (nblk * 4 + wave) * 16;
    const ushort* qn = qp + (size_t)(b * 4096 + n0 + cc) * (2 * D);
    short8 Ah[NF], Al[NF];
    if constexpr (D == 16) {
        Ah[0] = *(const short8*)(qn + quad * 8);   // [qh16|ql16] spans k=0..31
    } else {
#pragma unroll
        for (int h = 0; h < NF; ++h) {
            Ah[h] = *(const short8*)(qn + h * 32 + quad * 8);
            Al[h] = *(const short8*)(qn + D + h * 32 + quad * 8);
        }
    }
    float Sn[4] = {0.f, 0.f, 0.f, 0.f};
    float Sw[4] = {0.f, 0.f, 0.f, 0.f};
    int tbase = mc * 64;
    const uint4* gk = (const uint4*)(kf + (size_t)b * (256 * NC * 512) +
                                     (size_t)tbase * (NC * 512));
    const float* gs = srow + tbase * 16;

    // prologue: DMA stage 0 into buffer 0
#pragma unroll
    for (int i = 0; i < 4; ++i)
        gload_lds16(gk + tid + i * 256, (uint4*)kst[0] + tid + i * 256);
    if (tid < ST * 16) gload_lds4(gs + tid, &sst[0][tid]);

#pragma unroll 1
    for (int st = 0; st < NSTG; ++st) {
        int cur = st & 1;
        __syncthreads();   // drains DMA for buf[cur]
        if (st + 1 < NSTG) {
#pragma unroll
            for (int i = 0; i < 4; ++i)
                gload_lds16(gk + (size_t)(st + 1) * 1024 + tid + i * 256,
                            (uint4*)kst[cur ^ 1] + tid + i * 256);
            if (tid < ST * 16)
                gload_lds4(gs + (st + 1) * ST * 16 + tid, &sst[cur ^ 1][tid]);
        }
        const ushort* kl = kst[cur] + lane * 8;
#pragma unroll
        for (int t = 0; t < ST; ++t) {
            short8 Bf[NC];
#pragma unroll
            for (int cb = 0; cb < NC; ++cb)
                Bf[cb] = *(const short8*)(kl + (t * NC + cb) * 512);
            float sv = sst[cur][t * 16 + cc];
            f32x4 c = {0.f, 0.f, 0.f, 0.f};
            if constexpr (D == 16) {
                c = __builtin_amdgcn_mfma_f32_16x16x32_bf16(Ah[0], Bf[1], c, 0, 0, 0);
                c = __builtin_amdgcn_mfma_f32_16x16x32_bf16(Ah[0], Bf[0], c, 0, 0, 0);
            } else {
#pragma unroll
                for (int h = 0; h < NF; ++h) {
                    c = __builtin_amdgcn_mfma_f32_16x16x32_bf16(Ah[h], Bf[h * 2 + 1], c, 0, 0, 0);
                    c = __builtin_amdgcn_mfma_f32_16x16x32_bf16(Al[h], Bf[h * 2], c, 0, 0, 0);
                    c = __builtin_amdgcn_mfma_f32_16x16x32_bf16(Al[h], Bf[h * 2 + 1], c, 0, 0, 0);
                    c = __builtin_amdgcn_mfma_f32_16x16x32_bf16(Ah[h], Bf[h * 2], c, 0, 0, 0);
                }
            }
#pragma unroll
            for (int r = 0; r < 4; ++r) {
                float e = __builtin_amdgcn_exp2f(c[r]);
                Sn[r] += e;
                Sw[r] += e * sv;
            }
        }
    }
#pragma unroll
    for (int mask = 1; mask < 16; mask <<= 1) {
#pragma unroll
        for (int r = 0; r < 4; ++r) {
            Sn[r] += __shfl_xor(Sn[r], mask, 64);
            Sw[r] += __shfl_xor(Sw[r], mask, 64);
        }
    }
    if (cc == 0) {
        int n = n0 + quad * 4;
        int pidx = (b * 4 + mc) * 4096 + n;
        *(float4*)&pSn[pidx] = make_float4(Sn[0], Sn[1], Sn[2], Sn[3]);
        *(float4*)&pSw[pidx] = make_float4(Sw[0], Sw[1], Sw[2], Sw[3]);
    }
}

// --------------------------- attn: all three scales ------------------------
__global__ __launch_bounds__(256) void attn_kernel(float* ws) {
    __shared__ __align__(16) ushort kst[2][8192];   // 2 x 16 KB stage buffers
    __shared__ float sst[2][128];
    int idx = blockIdx.x, tid = threadIdx.x;
    int li = idx & 1023;
    int nblk = li & 63, mc = (li >> 6) & 3, b = li >> 8;
    if (idx < 1024) {
        attn_mfma_body<64>((const ushort*)(ws + OFF_QP0), (const ushort*)(ws + OFF_KF0),
                           ws + OFF_SBIG0 + b * 4096,
                           ws + OFF_PSN0, ws + OFF_PSW0, nblk, mc, b, tid, kst, sst);
    } else if (idx < 2048) {
        attn_mfma_body<32>((const ushort*)(ws + OFF_QP1), (const ushort*)(ws + OFF_KF1),
                           ws + OFF_SBIG1 + b * 4096,
                           ws + OFF_PSN1, ws + OFF_PSW1, nblk, mc, b, tid, kst, sst);
    } else {
        attn_mfma_body<16>((const ushort*)(ws + OFF_QP2), (const ushort*)(ws + OFF_KF2),
                           ws + OFF_PROJ2 + ((size_t)b * 65 + 32) * 4096,
                           ws + OFF_PSN2, ws + OFF_PSW2, nblk, mc, b, tid, kst, sst);
    }
}

// --------------------------- final: combine + fusion -----------------------
// 64-thread blocks (1 wave), 256 x BB grid: same per-thread work and
// accumulation order as before (bit-exact), but 4x the block count ->
// all 256 CUs get work (was 64 blocks -> 64 CUs, latency-bound).
__global__ __launch_bounds__(64) void final_kernel(const float* __restrict__ ws,
                                                   const float* __restrict__ ba0,
                                                   const float* __restrict__ ba1,
                                                   const float* __restrict__ ba2,
                                                   const float* __restrict__ b1,
                                                   const float* __restrict__ w2,
                                                   const float* __restrict__ b2,
                                                   float* __restrict__ out) {
    __shared__ float lb1[32], lw2[32];
    int tid = threadIdx.x;
    if (tid < 32) { lb1[tid] = b1[tid]; lw2[tid] = w2[tid]; }
    __syncthreads();
    int b = blockIdx.y;
    int n = blockIdx.x * 64 + tid;
    const float* pSns[3] = {ws + OFF_PSN0, ws + OFF_PSN1, ws + OFF_PSN2};
    const float* pSws[3] = {ws + OFF_PSW0, ws + OFF_PSW1, ws + OFF_PSW2};
    float aval[3];
#pragma unroll
    for (int s = 0; s < 3; ++s) {
        float Sn = 0.f, Sw = 0.f;
#pragma unroll
        for (int ch = 0; ch < 4; ++ch) {
            int pi = (b * 4 + ch) * 4096 + n;
            Sn += pSns[s][pi];
            Sw += pSws[s][pi];
        }
        float bav = (s == 0) ? ba0[0] : (s == 1) ? ba1[0] : ba2[0];
        aval[s] = Sw / Sn + bav;
    }
    float prod = aval[0] * aval[1] * aval[2];
    int oy = n >> 6, ox = n & 63;
    float f0 = 15.0f / 63.0f;
    float cy0 = oy * f0, cx0 = ox * f0;
    int iy0 = min((int)cy0, 14), ix0 = min((int)cx0, 14);
    float wy0 = cy0 - iy0, wx0 = cx0 - ix0;
    float f1 = 31.0f / 63.0f;
    float cy1 = oy * f1, cx1 = ox * f1;
    int iy1 = min((int)cy1, 30), ix1 = min((int)cx1, 30);
    float wy1 = cy1 - iy1, wx1 = cx1 - ix1;
    const float* g0b = ws + OFF_PROJ0 + (b * 161 + 129) * 256;
    const float* g1b = ws + OFF_PROJ1 + (b * 97 + 65) * 1024;
    const float* g2b = ws + OFF_PROJ2 + (b * 65 + 33) * 4096;
    float outv = 0.f;
#pragma unroll 4
    for (int j = 0; j < 32; ++j) {
        const float* p0 = g0b + j * 256;
        float v0 = (1.f - wy0) * ((1.f - wx0) * p0[iy0 * 16 + ix0] + wx0 * p0[iy0 * 16 + ix0 + 1]) +
                   wy0 * ((1.f - wx0) * p0[(iy0 + 1) * 16 + ix0] + wx0 * p0[(iy0 + 1) * 16 + ix0 + 1]);
        const float* p1 = g1b + j * 1024;
        float v1 = (1.f - wy1) * ((1.f - wx1) * p1[iy1 * 32 + ix1] + wx1 * p1[iy1 * 32 + ix1 + 1]) +
                   wy1 * ((1.f - wx1) * p1[(iy1 + 1) * 32 + ix1] + wx1 * p1[(iy1 + 1) * 32 + ix1 + 1]);
        float g = g2b[j * 4096 + n] + v0 + v1;
        float h = fmaxf(prod * g + lb1[j], 0.f);
        outv += lw2[j] * h;
    }
    out[b * 4096 + n] = outv + b2[0];
}

// ---------------------------------------------------------------------------
extern "C" void kernel_launch(void* const* d_in, const int* in_sizes, int n_in,
                              void* d_out, int out_size, void* d_ws, size_t ws_size,
                              hipStream_t stream) {
    const float* x3 = (const float*)d_in[0];
    const float* x2 = (const float*)d_in[1];
    const float* x1 = (const float*)d_in[2];
    const float* W[24];
    for (int i = 0; i < 24; ++i) W[i] = (const float*)d_in[3 + i];
    const float* w1 = (const float*)d_in[27];
    const float* b1 = (const float*)d_in[28];
    const float* w2 = (const float*)d_in[29];
    const float* b2 = (const float*)d_in[30];
    float* ws = (float*)d_ws;
    float* out = (float*)d_out;

    UArgs ua;
    ua.wv0 = W[4];  ua.wa0 = W[6];  ua.bv0 = W[5];
    ua.wv1 = W[12]; ua.wa1 = W[14]; ua.bv1 = W[13];
    ua.wv2 = W[20]; ua.wa2 = W[22]; ua.bv2 = W[21];
    ua.ws = ws;
    u_kernel<<<56, 256, 0, stream>>>(ua);

    ProjArgs ja;
    ja.x0 = x1; ja.x1 = x2; ja.x2 = x3;
    ja.wq0 = W[0];  ja.wk0 = W[2];  ja.bq0 = W[1];  ja.bk0 = W[3];
    ja.wq1 = W[8];  ja.wk1 = W[10]; ja.bq1 = W[9];  ja.bk1 = W[11];
    ja.wq2 = W[16]; ja.wk2 = W[18]; ja.bq2 = W[17]; ja.bk2 = W[19];
    ja.w1 = w1; ja.ws = ws;
    proj_kernel<<<952, 256, 0, stream>>>(ja);

    mid_kernel<<<640, 256, 0, stream>>>(ws);

    attn_kernel<<<3072, 256, 0, stream>>>(ws);

    final_kernel<<<dim3(64, BB), 64, 0, stream>>>(ws, W[7], W[15], W[23],
                                                  b1, w2, b2, out);
}

// Round 13
// 250.657 us; speedup vs baseline: 1.2282x; 1.0132x over previous
//
#include <hip/hip_runtime.h>

// ---------------------------------------------------------------------------
// MultiScaleFeatureFusion — R28 (= R27 with attn stage halved 16->8 KB).
//   scale0: x1 [4,512,16,16]  d=64 C=512 hs=16 Ns=256  R=161
//   scale1: x2 [4,256,32,32]  d=32 C=256 hs=32 Ns=1024 R=97
//   scale2: x3 [4,128,64,64]  d=16 C=128 hs=64 Ns=4096 R=65
// attn: double-buffered global_load_lds DMA staging. R27's 2x16KB buffers
// capped residency at 4 blocks/CU (37% occupancy) with MFMA 35%/VALU 48% —
// latency-bound, neither pipe saturated. 2x8KB buffers -> 16.9 KB LDS ->
// 8 blocks/CU = 32 waves/CU (full). Twice the barriers, but each DMA still
// has a full compute phase to land, and 8 resident blocks keep the CU fed
// through barrier waits. Same DMA traffic, same per-tile MFMA/exp order
// (bit-exact). Harness tax (256MiB poison-fill 42us + restores ~46us) is
// untouchable; final re-gridded to 64-thr blocks in R27.
// ---------------------------------------------------------------------------

#define BB 4
#define LOG2E 1.44269504088896340736f

typedef __attribute__((ext_vector_type(8))) short short8;
typedef __attribute__((ext_vector_type(4))) float f32x4;

static constexpr int OFF_UP0 = 0;                        // [4][512]
static constexpr int OFF_UP1 = OFF_UP0 + 4 * 512;
static constexpr int OFF_UP2 = OFF_UP1 + 4 * 256;
static constexpr int OFF_UB0 = OFF_UP2 + 4 * 128;
static constexpr int OFF_UB1 = OFF_UB0 + 4;
static constexpr int OFF_UB2 = OFF_UB1 + 4;
static constexpr int OFF_PROJ0 = OFF_UB2 + 4;
static constexpr int OFF_PROJ1 = OFF_PROJ0 + BB * 161 * 256;
static constexpr int OFF_PROJ2 = OFF_PROJ1 + BB * 97 * 1024;
static constexpr int OFF_SBIG0 = OFF_PROJ2 + BB * 65 * 4096;   // [b][4096]
static constexpr int OFF_SBIG1 = OFF_SBIG0 + BB * 4096;        // [b][4096]
static constexpr int OFF_QP0 = OFF_SBIG1 + BB * 4096;          // BB*4096*64 fl
static constexpr int OFF_KF0 = OFF_QP0 + BB * 4096 * 64;       // BB*262144 fl
static constexpr int OFF_QP1 = OFF_KF0 + BB * 262144;          // BB*4096*32 fl
static constexpr int OFF_KF1 = OFF_QP1 + BB * 4096 * 32;       // BB*131072 fl
static constexpr int OFF_QP2 = OFF_KF1 + BB * 131072;          // BB*4096*16 fl
static constexpr int OFF_KF2 = OFF_QP2 + BB * 4096 * 16;       // BB*131072 fl
static constexpr int PS = BB * 4 * 4096;
static constexpr int OFF_PSN0 = OFF_KF2 + BB * 131072;
static constexpr int OFF_PSW0 = OFF_PSN0 + PS;
static constexpr int OFF_PSN1 = OFF_PSW0 + PS;
static constexpr int OFF_PSW1 = OFF_PSN1 + PS;
static constexpr int OFF_PSN2 = OFF_PSW1 + PS;
static constexpr int OFF_PSW2 = OFF_PSN2 + PS;

// ---- direct global->LDS DMA helpers (size literal; dest = base+lane*sz) ---
__device__ inline void gload_lds16(const void* g, void* l) {
    __builtin_amdgcn_global_load_lds((const __attribute__((address_space(1))) void*)g,
                                     (__attribute__((address_space(3))) void*)l, 16, 0, 0);
}
__device__ inline void gload_lds4(const void* g, void* l) {
    __builtin_amdgcn_global_load_lds((const __attribute__((address_space(1))) void*)g,
                                     (__attribute__((address_space(3))) void*)l, 4, 0, 0);
}

// --------------------------- u partials ------------------------------------
struct UArgs {
    const float *wv0, *wa0, *bv0;
    const float *wv1, *wa1, *bv1;
    const float *wv2, *wa2, *bv2;
    float* ws;
};

__global__ void u_kernel(UArgs A) {
    __shared__ float red[256];
    int idx = blockIdx.x, tid = threadIdx.x;
    int C, cit, chunk;
    const float *wv, *wa, *bv;
    float *up, *ub;
    if (idx < 32) {
        C = 512; cit = idx >> 2; chunk = idx & 3;
        wv = A.wv0; wa = A.wa0; bv = A.bv0;
        up = A.ws + OFF_UP0; ub = A.ws + OFF_UB0;
    } else if (idx < 48) {
        int i2 = idx - 32;
        C = 256; cit = i2 >> 2; chunk = i2 & 3;
        wv = A.wv1; wa = A.wa1; bv = A.bv1;
        up = A.ws + OFF_UP1; ub = A.ws + OFF_UB1;
    } else {
        int i2 = idx - 48;
        C = 128; cit = i2 >> 2; chunk = i2 & 3;
        wv = A.wv2; wa = A.wa2; bv = A.bv2;
        up = A.ws + OFF_UP2; ub = A.ws + OFF_UB2;
    }
    int lci = tid & 63, sub = tid >> 6;
    int ci = cit * 64 + lci;
    int coBeg = chunk * (C >> 2), coEnd = coBeg + (C >> 2);
    float acc = 0.f;
#pragma unroll 4
    for (int co = coBeg + sub; co < coEnd; co += 4)
        acc += wa[co] * wv[(size_t)co * C + ci];
    red[tid] = acc;
    __syncthreads();
    if (sub == 0)
        up[chunk * C + ci] = red[lci] + red[lci + 64] + red[lci + 128] + red[lci + 192];
    if (cit == 0) {
        __syncthreads();
        float bacc = 0.f;
        for (int co = coBeg + tid; co < coEnd; co += 256) bacc += wa[co] * bv[co];
        red[tid] = bacc;
        __syncthreads();
        for (int off = 128; off > 0; off >>= 1) {
            if (tid < off) red[tid] += red[tid + off];
            __syncthreads();
        }
        if (tid == 0) ub[chunk] = red[0];
    }
}

// --------------------------- proj: all scales, 16 rows/block, 2 m/thread ---
struct ProjArgs {
    const float *x0, *x1, *x2;
    const float *wq0, *wk0, *bq0, *bk0;
    const float *wq1, *wk1, *bq1, *bk1;
    const float *wq2, *wk2, *bq2, *bk2;
    const float *w1;
    float* ws;
};

__global__ __launch_bounds__(256) void proj_kernel(ProjArgs A) {
    __shared__ __align__(16) float Wl[512 * 16];  // [c][rr]
    __shared__ float bl[16];
    __shared__ float red[2048];
    int idx = blockIdx.x, tid = threadIdx.x;
    const float *x, *wq, *wk, *bq, *bk, *up, *ub;
    float* out;
    int C, Ns, R, nx, d, w1off, local;
    if (idx < 88) {
        local = idx; x = A.x0; out = A.ws + OFF_PROJ0;
        wq = A.wq0; wk = A.wk0; bq = A.bq0; bk = A.bk0;
        up = A.ws + OFF_UP0; ub = A.ws + OFF_UB0;
        C = 512; Ns = 256; R = 161; nx = 2; d = 64; w1off = 384;
    } else if (idx < 312) {
        local = idx - 88; x = A.x1; out = A.ws + OFF_PROJ1;
        wq = A.wq1; wk = A.wk1; bq = A.bq1; bk = A.bk1;
        up = A.ws + OFF_UP1; ub = A.ws + OFF_UB1;
        C = 256; Ns = 1024; R = 97; nx = 8; d = 32; w1off = 128;
    } else {
        local = idx - 312; x = A.x2; out = A.ws + OFF_PROJ2;
        wq = A.wq2; wk = A.wk2; bq = A.bq2; bk = A.bk2;
        up = A.ws + OFF_UP2; ub = A.ws + OFF_UB2;
        C = 128; Ns = 4096; R = 65; nx = 32; d = 16; w1off = 0;
    }
    int ny = (R + 15) >> 4;
    int pb = nx * ny;
    int b = local / pb;
    int rem = local - b * pb;
    int by = rem / nx;
    int bx = rem - by * nx;
    int r0 = by * 16;
    int nr = min(16, R - r0);
    for (int rp = 0; rp < 16; rp += 8) {
        int rr = rp + (tid >> 5), cg = tid & 31;
        int gr = r0 + rr;
        if (gr == 2 * d) {
            for (int c = cg; c < C; c += 32)
                Wl[c * 16 + rr] = up[c] + up[C + c] + up[2 * C + c] + up[3 * C + c];
        } else {
            const float* rowsrc;
            if (gr < d) rowsrc = wq + (size_t)gr * C;
            else if (gr < 2 * d) rowsrc = wk + (size_t)(gr - d) * C;
            else if (gr < R) rowsrc = A.w1 + (size_t)(gr - 2 * d - 1) * 896 + w1off;
            else rowsrc = nullptr;
            if (rowsrc) {
                for (int c = cg; c < C; c += 32) Wl[c * 16 + rr] = rowsrc[c];
            } else {
                for (int c = cg; c < C; c += 32) Wl[c * 16 + rr] = 0.f;
            }
        }
    }
    if (tid < 16) {
        int g2 = r0 + tid;
        float bv2;
        if (g2 < d) bv2 = bq[g2];
        else if (g2 < 2 * d) bv2 = bk[g2 - d];
        else if (g2 == 2 * d) bv2 = ub[0] + ub[1] + ub[2] + ub[3];
        else bv2 = 0.f;
        bl[tid] = bv2;
    }
    __syncthreads();
    int lane = tid & 63, strip = tid >> 6;
    int m0 = bx * 128 + lane * 2;
    const float* xb = x + (size_t)(b * C) * Ns + m0;
    float acc[16][2];
#pragma unroll
    for (int r = 0; r < 16; ++r) {
        acc[r][0] = 0.f;
        acc[r][1] = 0.f;
    }
    float2 buf[4];
#pragma unroll
    for (int j = 0; j < 4; ++j)
        buf[j] = *(const float2*)&xb[(size_t)(strip + 4 * j) * Ns];
    for (int c0 = strip; c0 < C; c0 += 16) {
#pragma unroll
        for (int j = 0; j < 4; ++j) {
            int c = c0 + 4 * j;
            float2 xv = buf[j];
            int cn = c + 16;
            if (cn < C) buf[j] = *(const float2*)&xb[(size_t)cn * Ns];
            const float* wl = &Wl[c * 16];
#pragma unroll
            for (int r4 = 0; r4 < 4; ++r4) {
                float4 w = *(const float4*)&wl[r4 * 4];
                acc[r4 * 4 + 0][0] += w.x * xv.x; acc[r4 * 4 + 0][1] += w.x * xv.y;
                acc[r4 * 4 + 1][0] += w.y * xv.x; acc[r4 * 4 + 1][1] += w.y * xv.y;
                acc[r4 * 4 + 2][0] += w.z * xv.x; acc[r4 * 4 + 2][1] += w.z * xv.y;
                acc[r4 * 4 + 3][0] += w.w * xv.x; acc[r4 * 4 + 3][1] += w.w * xv.y;
            }
        }
    }
    for (int rp = 0; rp < 16; rp += 4) {
        __syncthreads();
#pragma unroll
        for (int r = 0; r < 4; ++r)
#pragma unroll
            for (int j = 0; j < 2; ++j)
                red[((r * 2 + j) * 4 + strip) * 64 + lane] = acc[rp + r][j];
        __syncthreads();
        int g = tid >> 6;
        int rr2 = rp + g;
        if (rr2 < nr) {
            float v[2];
#pragma unroll
            for (int j = 0; j < 2; ++j) {
                int base = (g * 2 + j) * 256 + lane;
                v[j] = red[base] + red[base + 64] + red[base + 128] + red[base + 192] + bl[rr2];
            }
            float2 v2; v2.x = v[0]; v2.y = v[1];
            *(float2*)&out[(size_t)(b * R + r0 + rr2) * Ns + m0] = v2;
        }
    }
}

// --------------------------- hi/lo split helper ----------------------------
__device__ inline void split_bf16(float f, ushort& hi, ushort& lo) {
    unsigned u = __float_as_uint(f);
    unsigned h = u >> 16;
    float r = f - __uint_as_float(h << 16);
    hi = (ushort)h;
    lo = (ushort)(__float_as_uint(r) >> 16);
}

// --------------------------- bilerp field values ---------------------------
template <int D, int HS>
__device__ void bilerp_vals(const float* __restrict__ proj, int R, int rowbase,
                            float scale, int b, int n, float* vals) {
    constexpr int NS = HS * HS;
    constexpr float f = (float)(HS - 1) / 63.0f;
    int oy = n >> 6, ox = n & 63;
    float cy = oy * f, cx = ox * f;
    int iy0 = min((int)cy, HS - 2);
    int ix0 = min((int)cx, HS - 2);
    float wy = cy - iy0, wx = cx - ix0;
    float w00 = (1.f - wy) * (1.f - wx) * scale, w01 = (1.f - wy) * wx * scale;
    float w10 = wy * (1.f - wx) * scale, w11 = wy * wx * scale;
    const float* pb = proj + ((size_t)b * R + rowbase) * NS + iy0 * HS + ix0;
#pragma unroll
    for (int d = 0; d < D; ++d) {
        const float* p = pb + (size_t)d * NS;
        vals[d] = w00 * p[0] + w01 * p[1] + w10 * p[HS] + w11 * p[HS + 1];
    }
}

// --------------------------- q pack ([n][2D] layout) -----------------------
template <int D>
__device__ void q_store(ushort* __restrict__ dst, const float* vals, int b, int n) {
    ushort outv[2 * D];
#pragma unroll
    for (int d = 0; d < D; ++d) split_bf16(vals[d], outv[d], outv[D + d]);
    ushort* dp = dst + (size_t)(b * 4096 + n) * (2 * D);
#pragma unroll
    for (int i = 0; i < D / 4; ++i)
        ((uint4*)dp)[i] = ((const uint4*)outv)[i];
}

// q pack for scale0, one 32-field chunk (chunk 0: d 0..31, chunk 1: 32..63).
__device__ void q_store_c32(ushort* __restrict__ dst, const float* vals,
                            int b, int n, int chunk) {
    ushort outv[64];
#pragma unroll
    for (int d = 0; d < 32; ++d) split_bf16(vals[d], outv[d], outv[32 + d]);
    ushort* dp = dst + (size_t)(b * 4096 + n) * 128;
#pragma unroll
    for (int i = 0; i < 4; ++i)
        ((uint4*)dp)[chunk * 4 + i] = ((const uint4*)outv)[i];
#pragma unroll
    for (int i = 0; i < 4; ++i)
        ((uint4*)dp)[8 + chunk * 4 + i] = ((const uint4*)outv)[4 + i];
}

// --------------------------- k pack (fragment order) -----------------------
template <int D>
__device__ void k_store(ushort* __restrict__ dst, const float* vals, int b, int n) {
    constexpr int NC = (D == 16) ? 2 : (D / 32) * 2;
    ushort hi[D], lo[D];
#pragma unroll
    for (int d = 0; d < D; ++d) split_bf16(vals[d], hi[d], lo[d]);
    int tile = n >> 4, cc = n & 15;
    ushort* kb = dst + (size_t)b * (256 * NC * 512) + (size_t)tile * (NC * 512);
    if constexpr (D == 16) {
#pragma unroll
        for (int combo = 0; combo < 2; ++combo)
#pragma unroll
            for (int quad = 0; quad < 4; ++quad) {
                const ushort* src = (combo == 0 ? hi : lo) + (quad & 1) * 8;
                ushort* dp = kb + ((size_t)combo * 512 + (quad * 16 + cc) * 8);
                *(uint4*)dp = *(const uint4*)src;
            }
    } else {
#pragma unroll
        for (int h = 0; h < D / 32; ++h)
#pragma unroll
            for (int part = 0; part < 2; ++part) {
                int combo = h * 2 + part;
#pragma unroll
                for (int quad = 0; quad < 4; ++quad) {
                    const ushort* src = (part == 0 ? hi : lo) + h * 32 + quad * 8;
                    ushort* dp = kb + ((size_t)combo * 512 + (quad * 16 + cc) * 8);
                    *(uint4*)dp = *(const uint4*)src;
                }
            }
    }
}

// k pack for scale0, one 32-field chunk (h = chunk): writes combos
// {chunk*2, chunk*2+1} — disjoint across chunks, bit-identical union.
__device__ void k_store_c32(ushort* __restrict__ dst, const float* vals,
                            int b, int n, int chunk) {
    ushort hi[32], lo[32];
#pragma unroll
    for (int d = 0; d < 32; ++d) split_bf16(vals[d], hi[d], lo[d]);
    int tile = n >> 4, cc = n & 15;
    ushort* kb = dst + (size_t)b * (256 * 4 * 512) + (size_t)tile * (4 * 512);
#pragma unroll
    for (int part = 0; part < 2; ++part) {
        int combo = chunk * 2 + part;
#pragma unroll
        for (int quad = 0; quad < 4; ++quad) {
            const ushort* src = (part == 0 ? hi : lo) + quad * 8;
            ushort* dp = kb + ((size_t)combo * 512 + (quad * 16 + cc) * 8);
            *(uint4*)dp = *(const uint4*)src;
        }
    }
}

// --------------------------- native field values (scale2) ------------------
__device__ void nat_vals(const float* __restrict__ proj, int rowbase, float scale,
                         int b, int n, float* vals) {
    const float* pb = proj + ((size_t)b * 65 + rowbase) * 4096 + n;
#pragma unroll
    for (int d = 0; d < 16; ++d) vals[d] = pb[(size_t)d * 4096] * scale;
}

// --------------------------- mid: upsample-s + packs -----------------------
__global__ __launch_bounds__(256) void mid_kernel(float* ws) {
    int idx = blockIdx.x, tid = threadIdx.x;
    if (idx < 128) {
        int gi = idx * 256 + tid;
        int seg = gi >> 14;
        int li = gi & 16383;
        int b = li >> 12, n = li & 4095;
        const float* src;
        float* dst;
        int hs;
        if (seg == 0) { src = ws + OFF_PROJ0 + (b * 161 + 128) * 256;  dst = ws + OFF_SBIG0; hs = 16; }
        else          { src = ws + OFF_PROJ1 + (b * 97 + 64) * 1024;   dst = ws + OFF_SBIG1; hs = 32; }
        int oy = n >> 6, ox = n & 63;
        float f = (float)(hs - 1) / 63.0f;
        float cy = oy * f, cx = ox * f;
        int iy0 = min((int)cy, hs - 2);
        int ix0 = min((int)cx, hs - 2);
        float wy = cy - iy0, wx = cx - ix0;
        float v00 = src[iy0 * hs + ix0], v01 = src[iy0 * hs + ix0 + 1];
        float v10 = src[(iy0 + 1) * hs + ix0], v11 = src[(iy0 + 1) * hs + ix0 + 1];
        float t0 = v00 + wx * (v01 - v00), t1 = v10 + wx * (v11 - v10);
        dst[b * 4096 + n] = t0 + wy * (t1 - t0);
    } else if (idx < 384) {
        int li = idx - 128;               // 0..255: scale0, 2 chunks
        int field = li >> 7;
        int rest = li & 127;
        int b = rest >> 5;
        int nt = (rest >> 1) & 15;
        int chunk = rest & 1;
        int n = nt * 256 + tid;
        float vals[32];
        if (field == 0) {
            bilerp_vals<32, 16>(ws + OFF_PROJ0, 161, chunk * 32, LOG2E, b, n, vals);
            q_store_c32((ushort*)(ws + OFF_QP0), vals, b, n, chunk);
        } else {
            bilerp_vals<32, 16>(ws + OFF_PROJ0, 161, 64 + chunk * 32, 1.0f, b, n, vals);
            k_store_c32((ushort*)(ws + OFF_KF0), vals, b, n, chunk);
        }
    } else if (idx < 512) {
        int li = idx - 384;
        int field = li >> 6, b = (li >> 4) & 3, nt = li & 15;
        int n = nt * 256 + tid;
        float vals[32];
        if (field == 0) {
            bilerp_vals<32, 32>(ws + OFF_PROJ1, 97, 0, LOG2E, b, n, vals);
            q_store<32>((ushort*)(ws + OFF_QP1), vals, b, n);
        } else {
            bilerp_vals<32, 32>(ws + OFF_PROJ1, 97, 32, 1.0f, b, n, vals);
            k_store<32>((ushort*)(ws + OFF_KF1), vals, b, n);
        }
    } else {
        int li = idx - 512;
        int field = li >> 6, b = (li >> 4) & 3, nt = li & 15;
        int n = nt * 256 + tid;
        float vals[16];
        if (field == 0) {
            nat_vals(ws + OFF_PROJ2, 0, LOG2E, b, n, vals);
            q_store<16>((ushort*)(ws + OFF_QP2), vals, b, n);
        } else {
            nat_vals(ws + OFF_PROJ2, 16, 1.0f, b, n, vals);
            k_store<16>((ushort*)(ws + OFF_KF2), vals, b, n);
        }
    }
}

// --------------------------- MFMA attention body ---------------------------
// Double-buffered DMA staging with 8 KB stages (2x8KB + sst = 16.9 KB LDS
// -> 8 blocks/CU = 32 waves, full occupancy). DMA for stage s+1 issues
// right after the stage-s barrier and lands during stage-s compute. Stage
// loop NOT unrolled (R24 lesson: full unroll -> 216 VGPR). Per-element
// MFMA/exp/accumulation order identical to R16 (bit-exact).
template <int D>
__device__ void attn_mfma_body(const ushort* __restrict__ qp, const ushort* __restrict__ kf,
                               const float* __restrict__ srow,
                               float* __restrict__ pSn, float* __restrict__ pSw,
                               int nblk, int mc, int b, int tid,
                               ushort (*kst)[4096], float (*sst)[64]) {
    constexpr int NC = (D == 16) ? 2 : (D / 32) * 2;
    constexpr int ST = 8 / NC;        // tiles per 8 KB stage
    constexpr int NF = (D >= 32) ? (D / 32) : 1;
    constexpr int NSTG = 64 / ST;     // stages per 1024-m chunk
    int wave = tid >> 6, lane = tid & 63;
    int cc = lane & 15, quad = lane >> 4;
    int n0 = (nblk * 4 + wave) * 16;
    const ushort* qn = qp + (size_t)(b * 4096 + n0 + cc) * (2 * D);
    short8 Ah[NF], Al[NF];
    if constexpr (D == 16) {
        Ah[0] = *(const short8*)(qn + quad * 8);   // [qh16|ql16] spans k=0..31
    } else {
#pragma unroll
        for (int h = 0; h < NF; ++h) {
            Ah[h] = *(const short8*)(qn + h * 32 + quad * 8);
            Al[h] = *(const short8*)(qn + D + h * 32 + quad * 8);
        }
    }
    float Sn[4] = {0.f, 0.f, 0.f, 0.f};
    float Sw[4] = {0.f, 0.f, 0.f, 0.f};
    int tbase = mc * 64;
    const uint4* gk = (const uint4*)(kf + (size_t)b * (256 * NC * 512) +
                                     (size_t)tbase * (NC * 512));
    const float* gs = srow + tbase * 16;

    // prologue: DMA stage 0 into buffer 0 (512 uint4 = 2 per thread)
#pragma unroll
    for (int i = 0; i < 2; ++i)
        gload_lds16(gk + tid + i * 256, (uint4*)kst[0] + tid + i * 256);
    if (tid < ST * 16) gload_lds4(gs + tid, &sst[0][tid]);

#pragma unroll 1
    for (int st = 0; st < NSTG; ++st) {
        int cur = st & 1;
        __syncthreads();   // drains DMA for buf[cur]
        if (st + 1 < NSTG) {
#pragma unroll
            for (int i = 0; i < 2; ++i)
                gload_lds16(gk + (size_t)(st + 1) * 512 + tid + i * 256,
                            (uint4*)kst[cur ^ 1] + tid + i * 256);
            if (tid < ST * 16)
                gload_lds4(gs + (st + 1) * ST * 16 + tid, &sst[cur ^ 1][tid]);
        }
        const ushort* kl = kst[cur] + lane * 8;
#pragma unroll
        for (int t = 0; t < ST; ++t) {
            short8 Bf[NC];
#pragma unroll
            for (int cb = 0; cb < NC; ++cb)
                Bf[cb] = *(const short8*)(kl + (t * NC + cb) * 512);
            float sv = sst[cur][t * 16 + cc];
            f32x4 c = {0.f, 0.f, 0.f, 0.f};
            if constexpr (D == 16) {
                c = __builtin_amdgcn_mfma_f32_16x16x32_bf16(Ah[0], Bf[1], c, 0, 0, 0);
                c = __builtin_amdgcn_mfma_f32_16x16x32_bf16(Ah[0], Bf[0], c, 0, 0, 0);
            } else {
#pragma unroll
                for (int h = 0; h < NF; ++h) {
                    c = __builtin_amdgcn_mfma_f32_16x16x32_bf16(Ah[h], Bf[h * 2 + 1], c, 0, 0, 0);
                    c = __builtin_amdgcn_mfma_f32_16x16x32_bf16(Al[h], Bf[h * 2], c, 0, 0, 0);
                    c = __builtin_amdgcn_mfma_f32_16x16x32_bf16(Al[h], Bf[h * 2 + 1], c, 0, 0, 0);
                    c = __builtin_amdgcn_mfma_f32_16x16x32_bf16(Ah[h], Bf[h * 2], c, 0, 0, 0);
                }
            }
#pragma unroll
            for (int r = 0; r < 4; ++r) {
                float e = __builtin_amdgcn_exp2f(c[r]);
                Sn[r] += e;
                Sw[r] += e * sv;
            }
        }
    }
#pragma unroll
    for (int mask = 1; mask < 16; mask <<= 1) {
#pragma unroll
        for (int r = 0; r < 4; ++r) {
            Sn[r] += __shfl_xor(Sn[r], mask, 64);
            Sw[r] += __shfl_xor(Sw[r], mask, 64);
        }
    }
    if (cc == 0) {
        int n = n0 + quad * 4;
        int pidx = (b * 4 + mc) * 4096 + n;
        *(float4*)&pSn[pidx] = make_float4(Sn[0], Sn[1], Sn[2], Sn[3]);
        *(float4*)&pSw[pidx] = make_float4(Sw[0], Sw[1], Sw[2], Sw[3]);
    }
}

// --------------------------- attn: all three scales ------------------------
__global__ __launch_bounds__(256) void attn_kernel(float* ws) {
    __shared__ __align__(16) ushort kst[2][4096];   // 2 x 8 KB stage buffers
    __shared__ float sst[2][64];
    int idx = blockIdx.x, tid = threadIdx.x;
    int li = idx & 1023;
    int nblk = li & 63, mc = (li >> 6) & 3, b = li >> 8;
    if (idx < 1024) {
        attn_mfma_body<64>((const ushort*)(ws + OFF_QP0), (const ushort*)(ws + OFF_KF0),
                           ws + OFF_SBIG0 + b * 4096,
                           ws + OFF_PSN0, ws + OFF_PSW0, nblk, mc, b, tid, kst, sst);
    } else if (idx < 2048) {
        attn_mfma_body<32>((const ushort*)(ws + OFF_QP1), (const ushort*)(ws + OFF_KF1),
                           ws + OFF_SBIG1 + b * 4096,
                           ws + OFF_PSN1, ws + OFF_PSW1, nblk, mc, b, tid, kst, sst);
    } else {
        attn_mfma_body<16>((const ushort*)(ws + OFF_QP2), (const ushort*)(ws + OFF_KF2),
                           ws + OFF_PROJ2 + ((size_t)b * 65 + 32) * 4096,
                           ws + OFF_PSN2, ws + OFF_PSW2, nblk, mc, b, tid, kst, sst);
    }
}

// --------------------------- final: combine + fusion -----------------------
// 64-thread blocks (1 wave), 256 x BB grid: same per-thread work and
// accumulation order (bit-exact), 4x CU coverage vs the old 64-block grid.
__global__ __launch_bounds__(64) void final_kernel(const float* __restrict__ ws,
                                                   const float* __restrict__ ba0,
                                                   const float* __restrict__ ba1,
                                                   const float* __restrict__ ba2,
                                                   const float* __restrict__ b1,
                                                   const float* __restrict__ w2,
                                                   const float* __restrict__ b2,
                                                   float* __restrict__ out) {
    __shared__ float lb1[32], lw2[32];
    int tid = threadIdx.x;
    if (tid < 32) { lb1[tid] = b1[tid]; lw2[tid] = w2[tid]; }
    __syncthreads();
    int b = blockIdx.y;
    int n = blockIdx.x * 64 + tid;
    const float* pSns[3] = {ws + OFF_PSN0, ws + OFF_PSN1, ws + OFF_PSN2};
    const float* pSws[3] = {ws + OFF_PSW0, ws + OFF_PSW1, ws + OFF_PSW2};
    float aval[3];
#pragma unroll
    for (int s = 0; s < 3; ++s) {
        float Sn = 0.f, Sw = 0.f;
#pragma unroll
        for (int ch = 0; ch < 4; ++ch) {
            int pi = (b * 4 + ch) * 4096 + n;
            Sn += pSns[s][pi];
            Sw += pSws[s][pi];
        }
        float bav = (s == 0) ? ba0[0] : (s == 1) ? ba1[0] : ba2[0];
        aval[s] = Sw / Sn + bav;
    }
    float prod = aval[0] * aval[1] * aval[2];
    int oy = n >> 6, ox = n & 63;
    float f0 = 15.0f / 63.0f;
    float cy0 = oy * f0, cx0 = ox * f0;
    int iy0 = min((int)cy0, 14), ix0 = min((int)cx0, 14);
    float wy0 = cy0 - iy0, wx0 = cx0 - ix0;
    float f1 = 31.0f / 63.0f;
    float cy1 = oy * f1, cx1 = ox * f1;
    int iy1 = min((int)cy1, 30), ix1 = min((int)cx1, 30);
    float wy1 = cy1 - iy1, wx1 = cx1 - ix1;
    const float* g0b = ws + OFF_PROJ0 + (b * 161 + 129) * 256;
    const float* g1b = ws + OFF_PROJ1 + (b * 97 + 65) * 1024;
    const float* g2b = ws + OFF_PROJ2 + (b * 65 + 33) * 4096;
    float outv = 0.f;
#pragma unroll 4
    for (int j = 0; j < 32; ++j) {
        const float* p0 = g0b + j * 256;
        float v0 = (1.f - wy0) * ((1.f - wx0) * p0[iy0 * 16 + ix0] + wx0 * p0[iy0 * 16 + ix0 + 1]) +
                   wy0 * ((1.f - wx0) * p0[(iy0 + 1) * 16 + ix0] + wx0 * p0[(iy0 + 1) * 16 + ix0 + 1]);
        const float* p1 = g1b + j * 1024;
        float v1 = (1.f - wy1) * ((1.f - wx1) * p1[iy1 * 32 + ix1] + wx1 * p1[iy1 * 32 + ix1 + 1]) +
                   wy1 * ((1.f - wx1) * p1[(iy1 + 1) * 32 + ix1] + wx1 * p1[(iy1 + 1) * 32 + ix1 + 1]);
        float g = g2b[j * 4096 + n] + v0 + v1;
        float h = fmaxf(prod * g + lb1[j], 0.f);
        outv += lw2[j] * h;
    }
    out[b * 4096 + n] = outv + b2[0];
}

// ---------------------------------------------------------------------------
extern "C" void kernel_launch(void* const* d_in, const int* in_sizes, int n_in,
                              void* d_out, int out_size, void* d_ws, size_t ws_size,
                              hipStream_t stream) {
    const float* x3 = (const float*)d_in[0];
    const float* x2 = (const float*)d_in[1];
    const float* x1 = (const float*)d_in[2];
    const float* W[24];
    for (int i = 0; i < 24; ++i) W[i] = (const float*)d_in[3 + i];
    const float* w1 = (const float*)d_in[27];
    const float* b1 = (const float*)d_in[28];
    const float* w2 = (const float*)d_in[29];
    const float* b2 = (const float*)d_in[30];
    float* ws = (float*)d_ws;
    float* out = (float*)d_out;

    UArgs ua;
    ua.wv0 = W[4];  ua.wa0 = W[6];  ua.bv0 = W[5];
    ua.wv1 = W[12]; ua.wa1 = W[14]; ua.bv1 = W[13];
    ua.wv2 = W[20]; ua.wa2 = W[22]; ua.bv2 = W[21];
    ua.ws = ws;
    u_kernel<<<56, 256, 0, stream>>>(ua);

    ProjArgs ja;
    ja.x0 = x1; ja.x1 = x2; ja.x2 = x3;
    ja.wq0 = W[0];  ja.wk0 = W[2];  ja.bq0 = W[1];  ja.bk0 = W[3];
    ja.wq1 = W[8];  ja.wk1 = W[10]; ja.bq1 = W[9];  ja.bk1 = W[11];
    ja.wq2 = W[16]; ja.wk2 = W[18]; ja.bq2 = W[17]; ja.bk2 = W[19];
    ja.w1 = w1; ja.ws = ws;
    proj_kernel<<<952, 256, 0, stream>>>(ja);

    mid_kernel<<<640, 256, 0, stream>>>(ws);

    attn_kernel<<<3072, 256, 0, stream>>>(ws);

    final_kernel<<<dim3(64, BB), 64, 0, stream>>>(ws, W[7], W[15], W[23],
                                                  b1, w2, b2, out);
}